// Round 2
// baseline (15436.162 us; speedup 1.0000x reference)
//
#include <hip/hip_runtime.h>
#include <math.h>

#define DD 256
#define KK 512
#define TM 128
#define TKC 128
#define NCHUNK 4
#define DSL 32
#define NSL 8
#define NSLICES 32
#define SPLIT 4

typedef float float4v __attribute__((ext_vector_type(4)));

__device__ __forceinline__ void gld_lds16(const void* g, void* l) {
    __builtin_amdgcn_global_load_lds((const __attribute__((address_space(1))) void*)g,
                                     (__attribute__((address_space(3))) void*)l, 16, 0, 0);
}

// ---------------------------------------------------------------------------
// argmin over K=512 centroids for a 128-point block.
// Round-2 change: SINGLE-buffered 32KB LDS + launch_bounds(256,4) so 4 blocks
// co-reside per CU (was 2).  Inter-block wave overlap replaces the double
// buffer: 4 independent blocks per CU cover each other's stage/barrier
// stalls, and the 782-block grid packs in one round instead of 1.53.
// ---------------------------------------------------------------------------
__global__ __launch_bounds__(256, 4)
void argmin_kernel(const float* __restrict__ x, const float* __restrict__ cent,
                   const float* __restrict__ xx, const float* __restrict__ cc,
                   const int N,
                   int* __restrict__ assign_out,
                   const int* __restrict__ prev, const int pstride,
                   unsigned int* __restrict__ mismatch)
{
    __shared__ float xs[TM * DSL];   // 16 KB
    __shared__ float cs[TKC * DSL];  // 16 KB

    const int tid  = threadIdx.x;
    const int w    = tid >> 6;
    const int lane = tid & 63;
    const int tr   = tid >> 4;   // 0..15 (point dim)
    const int tc   = tid & 15;   // 0..15 (centroid dim)
    const long long rowbase = (long long)blockIdx.x * TM;

    float minv[8]; int mini[8]; float xxr[8];
#pragma unroll
    for (int i = 0; i < 8; ++i) {
        minv[i] = __builtin_inff(); mini[i] = 0;
        int r = ((i >> 2) << 6) + (tr << 2) + (i & 3);
        long long p = rowbase + r; if (p > N - 1) p = N - 1;
        xxr[i] = xx[p];
    }

    const int r_st  = (w << 3) + (lane >> 3);
    const int slot4 = (lane & 7) << 2;

#define STAGE(S) do {                                                             \
        const int d0_    = ((S) & 7) * DSL;                                       \
        const int cbase_ = ((S) >> 3) * TKC;                                      \
        _Pragma("unroll")                                                         \
        for (int call = 0; call < 4; ++call) {                                    \
            int r  = (call << 5) + r_st;                                          \
            int dl = slot4 ^ (((r >> 2) & 7) << 2);                               \
            long long p = rowbase + r; if (p > N - 1) p = N - 1;                  \
            gld_lds16(x + p * DD + d0_ + dl, &xs[((call << 2) + w) << 8]);        \
            gld_lds16(cent + (long long)(cbase_ + r) * DD + d0_ + dl,             \
                      &cs[((call << 2) + w) << 8]);                               \
        }                                                                         \
    } while (0)

    STAGE(0);
    int s = 0;
    float acc[8][8];

#pragma unroll 1
    for (int chunk = 0; chunk < NCHUNK; ++chunk) {
        float ccr[8];
#pragma unroll
        for (int j = 0; j < 8; ++j) {
            int r = ((j >> 2) << 6) + (tc << 2) + (j & 3);
            ccr[j] = cc[chunk * TKC + r];
        }
#pragma unroll
        for (int i = 0; i < 8; ++i)
#pragma unroll
            for (int j = 0; j < 8; ++j) acc[i][j] = 0.0f;

#pragma unroll 1
        for (int sl = 0; sl < NSL; ++sl) {
            __syncthreads();                  // staging for slice s visible (vmcnt drained)
#pragma unroll
            for (int g = 0; g < 8; ++g) {
                const int dl = g << 2;
                float4v ax[8], bc[8];
#pragma unroll
                for (int i = 0; i < 8; ++i) {
                    int r = ((i >> 2) << 6) + (tr << 2) + (i & 3);
                    ax[i] = *(const float4v*)&xs[(r << 5) + (dl ^ (((r >> 2) & 7) << 2))];
                }
#pragma unroll
                for (int j = 0; j < 8; ++j) {
                    int r = ((j >> 2) << 6) + (tc << 2) + (j & 3);
                    bc[j] = *(const float4v*)&cs[(r << 5) + (dl ^ (((r >> 2) & 7) << 2))];
                }
#pragma unroll
                for (int i = 0; i < 8; ++i)
#pragma unroll
                    for (int j = 0; j < 8; ++j) {
                        float t = acc[i][j];
                        t = fmaf(ax[i][0], bc[j][0], t);
                        t = fmaf(ax[i][1], bc[j][1], t);
                        t = fmaf(ax[i][2], bc[j][2], t);
                        t = fmaf(ax[i][3], bc[j][3], t);
                        acc[i][j] = t;
                    }
            }
            __syncthreads();                  // all waves done reading this slice
            if (s + 1 < NSLICES) STAGE(s + 1);
            ++s;
        }
        // fold this chunk into running min (registers only) — also covers the
        // in-flight staging latency of the next slice
        {
#pragma clang fp contract(off)
#pragma unroll
            for (int i = 0; i < 8; ++i)
#pragma unroll
                for (int j = 0; j < 8; ++j) {
                    int r = ((j >> 2) << 6) + (tc << 2) + (j & 3);
                    float t    = xxr[i] + ccr[j];
                    float d2   = t - 2.0f * acc[i][j];
                    float dist = sqrtf(fmaxf(d2, 0.0f));
                    if (dist < minv[i]) { minv[i] = dist; mini[i] = chunk * TKC + r; }
                }
        }
    }
#undef STAGE

    // reduce across the 16 tc lanes (bits 0..3 of lane), first-min tie-break
#pragma unroll
    for (int i = 0; i < 8; ++i) {
#pragma unroll
        for (int off = 1; off < 16; off <<= 1) {
            float ov = __shfl_xor(minv[i], off);
            int   oi = __shfl_xor(mini[i], off);
            if (ov < minv[i] || (ov == minv[i] && oi < mini[i])) { minv[i] = ov; mini[i] = oi; }
        }
    }
    if (tc == 0) {
        unsigned int mis = 0;
#pragma unroll
        for (int i = 0; i < 8; ++i) {
            long long p = rowbase + ((i >> 2) << 6) + (tr << 2) + (i & 3);
            if (p < N) {
                assign_out[p] = mini[i];
                if (prev != nullptr && prev[p * pstride] != mini[i]) ++mis;
            }
        }
        if (mis) atomicAdd(mismatch, mis);
    }
}

// row-wise squared norms (one wave per row, 256 cols)
__global__ void sqnorm_kernel(const float* __restrict__ m, float* __restrict__ out, const int n)
{
    const int w = threadIdx.x >> 6, lane = threadIdx.x & 63;
    const int row = (blockIdx.x << 2) + w;
    if (row >= n) return;
    const float4v v = *(const float4v*)&m[(long long)row * DD + (lane << 2)];
    float s = v[0]*v[0] + v[1]*v[1] + v[2]*v[2] + v[3]*v[3];
#pragma unroll
    for (int off = 1; off < 64; off <<= 1) s += __shfl_xor(s, off);
    if (lane == 0) out[row] = s;
}

// ---------------------------------------------------------------------------
// Segment-sum via counting sort + gather (replaces the 25.6M-atomic accum).
// Q40 fixed-point accumulation is order-independent => deterministic.
// ---------------------------------------------------------------------------
__global__ void hist_kernel(const int* __restrict__ assign, int* __restrict__ counts, const int N)
{
    const int p = blockIdx.x * 256 + threadIdx.x;
    if (p < N) atomicAdd(&counts[assign[p]], 1);
}

__global__ __launch_bounds__(KK)
void scan_kernel(const int* __restrict__ counts, int* __restrict__ starts, int* __restrict__ cursor)
{
    __shared__ int buf[2][KK];
    const int t = threadIdx.x;
    const int v = counts[t];
    buf[0][t] = v;
    __syncthreads();
    int src = 0;
#pragma unroll
    for (int off = 1; off < KK; off <<= 1) {
        int val = buf[src][t];
        if (t >= off) val += buf[src][t - off];
        buf[src ^ 1][t] = val;
        src ^= 1;
        __syncthreads();
    }
    const int excl = buf[src][t] - v;
    starts[t] = excl;
    cursor[t] = excl;
}

__global__ void scatter_kernel(const int* __restrict__ assign, int* __restrict__ cursor,
                               int* __restrict__ idx, const int N)
{
    const int p = blockIdx.x * 256 + threadIdx.x;
    if (p >= N) return;
    const int a = assign[p];
    const int pos = atomicAdd(&cursor[a], 1);
    idx[pos] = p;
}

__global__ __launch_bounds__(256)
void gather_kernel(const float* __restrict__ x, const int* __restrict__ idx,
                   const int* __restrict__ starts, const int* __restrict__ counts,
                   unsigned long long* __restrict__ sums)
{
    const int c    = blockIdx.x / SPLIT;
    const int part = blockIdx.x % SPLIT;
    const int d    = threadIdx.x;
    const int start = starts[c], cnt = counts[c];
    const int chunk = (cnt + SPLIT - 1) / SPLIT;
    const int i0 = part * chunk;
    int i1 = i0 + chunk; if (i1 > cnt) i1 = cnt;
    if (i1 <= i0) return;

    long long acc = 0;
    int i = i0;
    for (; i + 4 <= i1; i += 4) {
        const int p0 = idx[start + i + 0];
        const int p1 = idx[start + i + 1];
        const int p2 = idx[start + i + 2];
        const int p3 = idx[start + i + 3];
        const float v0 = x[(long long)p0 * DD + d];
        const float v1 = x[(long long)p1 * DD + d];
        const float v2 = x[(long long)p2 * DD + d];
        const float v3 = x[(long long)p3 * DD + d];
        acc += __double2ll_rn((double)v0 * 1099511627776.0);   // 2^40
        acc += __double2ll_rn((double)v1 * 1099511627776.0);
        acc += __double2ll_rn((double)v2 * 1099511627776.0);
        acc += __double2ll_rn((double)v3 * 1099511627776.0);
    }
    for (; i < i1; ++i) {
        const int p = idx[start + i];
        acc += __double2ll_rn((double)x[(long long)p * DD + d] * 1099511627776.0);
    }
    atomicAdd(&sums[(size_t)c * DD + d], (unsigned long long)acc);
}

// EMA update + squared norms of updated centroids
__global__ void update_kernel(const float* __restrict__ cent,
                              const unsigned long long* __restrict__ sums,
                              const int* __restrict__ counts,
                              float* __restrict__ updated, float* __restrict__ cc2)
{
    const int c = blockIdx.x, d = threadIdx.x;
    const int w = d >> 6, lane = d & 63;
    __shared__ float red[4];
    float u;
    {
#pragma clang fp contract(off)
        const float cnt = (float)counts[c];
        const float sf  = (float)((double)(long long)sums[(size_t)c * DD + d] * (1.0 / 1099511627776.0));
        const float nc  = sf / cnt;
        u = 0.01f * cent[(size_t)c * DD + d] + 0.99f * nc;
    }
    updated[(size_t)c * DD + d] = u;
    float s = u * u;
#pragma unroll
    for (int off = 1; off < 64; off <<= 1) s += __shfl_xor(s, off);
    if (lane == 0) red[w] = s;
    __syncthreads();
    if (d == 0) cc2[c] = (red[0] + red[1]) + (red[2] + red[3]);
}

// final select per match flag; everything emitted as f32
__global__ void output_kernel(const unsigned int* __restrict__ mismatch,
                              const int* __restrict__ a1, const int* __restrict__ a2,
                              const float* __restrict__ cent, const float* __restrict__ updated,
                              float* __restrict__ out, const int N, const int total)
{
    const int g = blockIdx.x * 256 + threadIdx.x;
    if (g >= total) return;
    const bool match = (*mismatch == 0u);
    if (g < N)       out[g] = (float)(match ? a2[g] : a1[g]);
    else if (g == N) out[g] = match ? 1.0f : 0.0f;
    else {
        const int e = g - N - 1;
        out[g] = match ? updated[e] : cent[e];
    }
}

extern "C" void kernel_launch(void* const* d_in, const int* in_sizes, int n_in,
                              void* d_out, int out_size, void* d_ws, size_t ws_size,
                              hipStream_t stream)
{
    const float* x    = (const float*)d_in[0];
    const float* cent = (const float*)d_in[1];
    const int*   prev = (const int*)d_in[2];
    const int N = in_sizes[0] / DD;
    const int pstride = (n_in >= 3 && in_sizes[2] >= 2 * N) ? 2 : 1;  // int64 defensive

    char* ws = (char*)d_ws;
    size_t off = 0;
    auto alloc = [&](size_t b) { void* p = ws + off; off += (b + 255) & ~(size_t)255; return p; };
    int*   assign1 = (int*)alloc((size_t)N * 4);
    int*   assign2 = (int*)alloc((size_t)N * 4);
    float* xx      = (float*)alloc((size_t)N * 4);
    float* cc      = (float*)alloc(KK * 4);
    float* cc2v    = (float*)alloc(KK * 4);
    int*   counts  = (int*)alloc(KK * 4);
    int*   starts  = (int*)alloc(KK * 4);
    int*   cursor  = (int*)alloc(KK * 4);
    int*   idx     = (int*)alloc((size_t)N * 4);
    unsigned long long* sums = (unsigned long long*)alloc((size_t)KK * DD * 8);
    float* updated = (float*)alloc((size_t)KK * DD * 4);
    unsigned int* mismatch = (unsigned int*)alloc(256);

    hipMemsetAsync(counts, 0, KK * 4, stream);
    hipMemsetAsync(sums, 0, (size_t)KK * DD * 8, stream);
    hipMemsetAsync(mismatch, 0, 4, stream);

    sqnorm_kernel<<<(N + 3) / 4, 256, 0, stream>>>(x, xx, N);
    sqnorm_kernel<<<(KK + 3) / 4, 256, 0, stream>>>(cent, cc, KK);

    const int gb = (N + TM - 1) / TM;
    argmin_kernel<<<gb, 256, 0, stream>>>(x, cent, xx, cc, N, assign1, prev, pstride, mismatch);

    // counting-sort + gather segment sum (replaces atomic accum_kernel)
    hist_kernel<<<(N + 255) / 256, 256, 0, stream>>>(assign1, counts, N);
    scan_kernel<<<1, KK, 0, stream>>>(counts, starts, cursor);
    scatter_kernel<<<(N + 255) / 256, 256, 0, stream>>>(assign1, cursor, idx, N);
    gather_kernel<<<KK * SPLIT, 256, 0, stream>>>(x, idx, starts, counts, sums);

    update_kernel<<<KK, 256, 0, stream>>>(cent, sums, counts, updated, cc2v);

    argmin_kernel<<<gb, 256, 0, stream>>>(x, updated, xx, cc2v, N, assign2, nullptr, 1, nullptr);

    output_kernel<<<(out_size + 255) / 256, 256, 0, stream>>>(mismatch, assign1, assign2,
                                                              cent, updated, (float*)d_out,
                                                              N, out_size);
}

// Round 3
// 11555.662 us; speedup vs baseline: 1.3358x; 1.3358x over previous
//
#include <hip/hip_runtime.h>
#include <math.h>

#define DD 256
#define KK 512
#define TM 128
#define TKC 128
#define NCHUNK 4
#define DSL 32
#define NSL 8
#define NSLICES 32
#define SPLIT 4

typedef float float4v __attribute__((ext_vector_type(4)));

__device__ __forceinline__ void gld_lds16(const void* g, void* l) {
    __builtin_amdgcn_global_load_lds((const __attribute__((address_space(1))) void*)g,
                                     (__attribute__((address_space(3))) void*)l, 16, 0, 0);
}

// ---------------------------------------------------------------------------
// argmin over K=512 centroids for a 128-point block.
// Round-3: single-buffered 32KB LDS (4 blocks/CU from LDS+VGPR limits) with
// launch_bounds(256,2).  Round-2 lesson: launch_bounds(256,4) forced the
// allocator to 64 VGPR -> acc[8][8] spilled to scratch -> 24GB of HBM spill
// traffic.  (256,2) compiled this core to exactly 128 VGPR in round 1; with
// 32KB LDS the HARDWARE then co-schedules 4 blocks/CU (512/128 = 4 waves/SIMD)
// without coercing the allocator.  Single-buffer exposes the per-slice stage
// latency within a block; the 3 other resident blocks cover it.
// ---------------------------------------------------------------------------
__global__ __launch_bounds__(256, 2)
void argmin_kernel(const float* __restrict__ x, const float* __restrict__ cent,
                   const float* __restrict__ xx, const float* __restrict__ cc,
                   const int N,
                   int* __restrict__ assign_out,
                   const int* __restrict__ prev, const int pstride,
                   unsigned int* __restrict__ mismatch)
{
    __shared__ float xs[TM * DSL];   // 16 KB
    __shared__ float cs[TKC * DSL];  // 16 KB

    const int tid  = threadIdx.x;
    const int w    = tid >> 6;
    const int lane = tid & 63;
    const int tr   = tid >> 4;   // 0..15 (point dim)
    const int tc   = tid & 15;   // 0..15 (centroid dim)
    const long long rowbase = (long long)blockIdx.x * TM;

    float minv[8]; int mini[8]; float xxr[8];
#pragma unroll
    for (int i = 0; i < 8; ++i) {
        minv[i] = __builtin_inff(); mini[i] = 0;
        int r = ((i >> 2) << 6) + (tr << 2) + (i & 3);
        long long p = rowbase + r; if (p > N - 1) p = N - 1;
        xxr[i] = xx[p];
    }

    const int r_st  = (w << 3) + (lane >> 3);
    const int slot4 = (lane & 7) << 2;

#define STAGE(S) do {                                                             \
        const int d0_    = ((S) & 7) * DSL;                                       \
        const int cbase_ = ((S) >> 3) * TKC;                                      \
        _Pragma("unroll")                                                         \
        for (int call = 0; call < 4; ++call) {                                    \
            int r  = (call << 5) + r_st;                                          \
            int dl = slot4 ^ (((r >> 2) & 7) << 2);                               \
            long long p = rowbase + r; if (p > N - 1) p = N - 1;                  \
            gld_lds16(x + p * DD + d0_ + dl, &xs[((call << 2) + w) << 8]);        \
            gld_lds16(cent + (long long)(cbase_ + r) * DD + d0_ + dl,             \
                      &cs[((call << 2) + w) << 8]);                               \
        }                                                                         \
    } while (0)

    STAGE(0);
    int s = 0;
    float acc[8][8];

#pragma unroll 1
    for (int chunk = 0; chunk < NCHUNK; ++chunk) {
        float ccr[8];
#pragma unroll
        for (int j = 0; j < 8; ++j) {
            int r = ((j >> 2) << 6) + (tc << 2) + (j & 3);
            ccr[j] = cc[chunk * TKC + r];
        }
#pragma unroll
        for (int i = 0; i < 8; ++i)
#pragma unroll
            for (int j = 0; j < 8; ++j) acc[i][j] = 0.0f;

#pragma unroll 1
        for (int sl = 0; sl < NSL; ++sl) {
            __syncthreads();                  // staging for slice s visible (vmcnt drained)
#pragma unroll
            for (int g = 0; g < 8; ++g) {
                const int dl = g << 2;
                float4v ax[8], bc[8];
#pragma unroll
                for (int i = 0; i < 8; ++i) {
                    int r = ((i >> 2) << 6) + (tr << 2) + (i & 3);
                    ax[i] = *(const float4v*)&xs[(r << 5) + (dl ^ (((r >> 2) & 7) << 2))];
                }
#pragma unroll
                for (int j = 0; j < 8; ++j) {
                    int r = ((j >> 2) << 6) + (tc << 2) + (j & 3);
                    bc[j] = *(const float4v*)&cs[(r << 5) + (dl ^ (((r >> 2) & 7) << 2))];
                }
#pragma unroll
                for (int i = 0; i < 8; ++i)
#pragma unroll
                    for (int j = 0; j < 8; ++j) {
                        float t = acc[i][j];
                        t = fmaf(ax[i][0], bc[j][0], t);
                        t = fmaf(ax[i][1], bc[j][1], t);
                        t = fmaf(ax[i][2], bc[j][2], t);
                        t = fmaf(ax[i][3], bc[j][3], t);
                        acc[i][j] = t;
                    }
            }
            __syncthreads();                  // all waves done reading this slice
            if (s + 1 < NSLICES) STAGE(s + 1);
            ++s;
        }
        // fold this chunk into running min (registers only) — also covers the
        // in-flight staging latency of the next slice
        {
#pragma clang fp contract(off)
#pragma unroll
            for (int i = 0; i < 8; ++i)
#pragma unroll
                for (int j = 0; j < 8; ++j) {
                    int r = ((j >> 2) << 6) + (tc << 2) + (j & 3);
                    float t    = xxr[i] + ccr[j];
                    float d2   = t - 2.0f * acc[i][j];
                    float dist = sqrtf(fmaxf(d2, 0.0f));
                    if (dist < minv[i]) { minv[i] = dist; mini[i] = chunk * TKC + r; }
                }
        }
    }
#undef STAGE

    // reduce across the 16 tc lanes (bits 0..3 of lane), first-min tie-break
#pragma unroll
    for (int i = 0; i < 8; ++i) {
#pragma unroll
        for (int off = 1; off < 16; off <<= 1) {
            float ov = __shfl_xor(minv[i], off);
            int   oi = __shfl_xor(mini[i], off);
            if (ov < minv[i] || (ov == minv[i] && oi < mini[i])) { minv[i] = ov; mini[i] = oi; }
        }
    }
    if (tc == 0) {
        unsigned int mis = 0;
#pragma unroll
        for (int i = 0; i < 8; ++i) {
            long long p = rowbase + ((i >> 2) << 6) + (tr << 2) + (i & 3);
            if (p < N) {
                assign_out[p] = mini[i];
                if (prev != nullptr && prev[p * pstride] != mini[i]) ++mis;
            }
        }
        if (mis) atomicAdd(mismatch, mis);
    }
}

// row-wise squared norms (one wave per row, 256 cols)
__global__ void sqnorm_kernel(const float* __restrict__ m, float* __restrict__ out, const int n)
{
    const int w = threadIdx.x >> 6, lane = threadIdx.x & 63;
    const int row = (blockIdx.x << 2) + w;
    if (row >= n) return;
    const float4v v = *(const float4v*)&m[(long long)row * DD + (lane << 2)];
    float s = v[0]*v[0] + v[1]*v[1] + v[2]*v[2] + v[3]*v[3];
#pragma unroll
    for (int off = 1; off < 64; off <<= 1) s += __shfl_xor(s, off);
    if (lane == 0) out[row] = s;
}

// ---------------------------------------------------------------------------
// Segment-sum via counting sort + gather (replaces the 25.6M-atomic accum).
// Q40 fixed-point accumulation is order-independent => deterministic.
// ---------------------------------------------------------------------------
__global__ void hist_kernel(const int* __restrict__ assign, int* __restrict__ counts, const int N)
{
    const int p = blockIdx.x * 256 + threadIdx.x;
    if (p < N) atomicAdd(&counts[assign[p]], 1);
}

__global__ __launch_bounds__(KK)
void scan_kernel(const int* __restrict__ counts, int* __restrict__ starts, int* __restrict__ cursor)
{
    __shared__ int buf[2][KK];
    const int t = threadIdx.x;
    const int v = counts[t];
    buf[0][t] = v;
    __syncthreads();
    int src = 0;
#pragma unroll
    for (int off = 1; off < KK; off <<= 1) {
        int val = buf[src][t];
        if (t >= off) val += buf[src][t - off];
        buf[src ^ 1][t] = val;
        src ^= 1;
        __syncthreads();
    }
    const int excl = buf[src][t] - v;
    starts[t] = excl;
    cursor[t] = excl;
}

__global__ void scatter_kernel(const int* __restrict__ assign, int* __restrict__ cursor,
                               int* __restrict__ idx, const int N)
{
    const int p = blockIdx.x * 256 + threadIdx.x;
    if (p >= N) return;
    const int a = assign[p];
    const int pos = atomicAdd(&cursor[a], 1);
    idx[pos] = p;
}

__global__ __launch_bounds__(256)
void gather_kernel(const float* __restrict__ x, const int* __restrict__ idx,
                   const int* __restrict__ starts, const int* __restrict__ counts,
                   unsigned long long* __restrict__ sums)
{
    const int c    = blockIdx.x / SPLIT;
    const int part = blockIdx.x % SPLIT;
    const int d    = threadIdx.x;
    const int start = starts[c], cnt = counts[c];
    const int chunk = (cnt + SPLIT - 1) / SPLIT;
    const int i0 = part * chunk;
    int i1 = i0 + chunk; if (i1 > cnt) i1 = cnt;
    if (i1 <= i0) return;

    long long acc = 0;
    int i = i0;
    for (; i + 4 <= i1; i += 4) {
        const int p0 = idx[start + i + 0];
        const int p1 = idx[start + i + 1];
        const int p2 = idx[start + i + 2];
        const int p3 = idx[start + i + 3];
        const float v0 = x[(long long)p0 * DD + d];
        const float v1 = x[(long long)p1 * DD + d];
        const float v2 = x[(long long)p2 * DD + d];
        const float v3 = x[(long long)p3 * DD + d];
        acc += __double2ll_rn((double)v0 * 1099511627776.0);   // 2^40
        acc += __double2ll_rn((double)v1 * 1099511627776.0);
        acc += __double2ll_rn((double)v2 * 1099511627776.0);
        acc += __double2ll_rn((double)v3 * 1099511627776.0);
    }
    for (; i < i1; ++i) {
        const int p = idx[start + i];
        acc += __double2ll_rn((double)x[(long long)p * DD + d] * 1099511627776.0);
    }
    atomicAdd(&sums[(size_t)c * DD + d], (unsigned long long)acc);
}

// EMA update + squared norms of updated centroids
__global__ void update_kernel(const float* __restrict__ cent,
                              const unsigned long long* __restrict__ sums,
                              const int* __restrict__ counts,
                              float* __restrict__ updated, float* __restrict__ cc2)
{
    const int c = blockIdx.x, d = threadIdx.x;
    const int w = d >> 6, lane = d & 63;
    __shared__ float red[4];
    float u;
    {
#pragma clang fp contract(off)
        const float cnt = (float)counts[c];
        const float sf  = (float)((double)(long long)sums[(size_t)c * DD + d] * (1.0 / 1099511627776.0));
        const float nc  = sf / cnt;
        u = 0.01f * cent[(size_t)c * DD + d] + 0.99f * nc;
    }
    updated[(size_t)c * DD + d] = u;
    float s = u * u;
#pragma unroll
    for (int off = 1; off < 64; off <<= 1) s += __shfl_xor(s, off);
    if (lane == 0) red[w] = s;
    __syncthreads();
    if (d == 0) cc2[c] = (red[0] + red[1]) + (red[2] + red[3]);
}

// final select per match flag; everything emitted as f32
__global__ void output_kernel(const unsigned int* __restrict__ mismatch,
                              const int* __restrict__ a1, const int* __restrict__ a2,
                              const float* __restrict__ cent, const float* __restrict__ updated,
                              float* __restrict__ out, const int N, const int total)
{
    const int g = blockIdx.x * 256 + threadIdx.x;
    if (g >= total) return;
    const bool match = (*mismatch == 0u);
    if (g < N)       out[g] = (float)(match ? a2[g] : a1[g]);
    else if (g == N) out[g] = match ? 1.0f : 0.0f;
    else {
        const int e = g - N - 1;
        out[g] = match ? updated[e] : cent[e];
    }
}

extern "C" void kernel_launch(void* const* d_in, const int* in_sizes, int n_in,
                              void* d_out, int out_size, void* d_ws, size_t ws_size,
                              hipStream_t stream)
{
    const float* x    = (const float*)d_in[0];
    const float* cent = (const float*)d_in[1];
    const int*   prev = (const int*)d_in[2];
    const int N = in_sizes[0] / DD;
    const int pstride = (n_in >= 3 && in_sizes[2] >= 2 * N) ? 2 : 1;  // int64 defensive

    char* ws = (char*)d_ws;
    size_t off = 0;
    auto alloc = [&](size_t b) { void* p = ws + off; off += (b + 255) & ~(size_t)255; return p; };
    int*   assign1 = (int*)alloc((size_t)N * 4);
    int*   assign2 = (int*)alloc((size_t)N * 4);
    float* xx      = (float*)alloc((size_t)N * 4);
    float* cc      = (float*)alloc(KK * 4);
    float* cc2v    = (float*)alloc(KK * 4);
    int*   counts  = (int*)alloc(KK * 4);
    int*   starts  = (int*)alloc(KK * 4);
    int*   cursor  = (int*)alloc(KK * 4);
    int*   idx     = (int*)alloc((size_t)N * 4);
    unsigned long long* sums = (unsigned long long*)alloc((size_t)KK * DD * 8);
    float* updated = (float*)alloc((size_t)KK * DD * 4);
    unsigned int* mismatch = (unsigned int*)alloc(256);

    hipMemsetAsync(counts, 0, KK * 4, stream);
    hipMemsetAsync(sums, 0, (size_t)KK * DD * 8, stream);
    hipMemsetAsync(mismatch, 0, 4, stream);

    sqnorm_kernel<<<(N + 3) / 4, 256, 0, stream>>>(x, xx, N);
    sqnorm_kernel<<<(KK + 3) / 4, 256, 0, stream>>>(cent, cc, KK);

    const int gb = (N + TM - 1) / TM;
    argmin_kernel<<<gb, 256, 0, stream>>>(x, cent, xx, cc, N, assign1, prev, pstride, mismatch);

    // counting-sort + gather segment sum (replaces atomic accum_kernel)
    hist_kernel<<<(N + 255) / 256, 256, 0, stream>>>(assign1, counts, N);
    scan_kernel<<<1, KK, 0, stream>>>(counts, starts, cursor);
    scatter_kernel<<<(N + 255) / 256, 256, 0, stream>>>(assign1, cursor, idx, N);
    gather_kernel<<<KK * SPLIT, 256, 0, stream>>>(x, idx, starts, counts, sums);

    update_kernel<<<KK, 256, 0, stream>>>(cent, sums, counts, updated, cc2v);

    argmin_kernel<<<gb, 256, 0, stream>>>(x, updated, xx, cc2v, N, assign2, nullptr, 1, nullptr);

    output_kernel<<<(out_size + 255) / 256, 256, 0, stream>>>(mismatch, assign1, assign2,
                                                              cent, updated, (float*)d_out,
                                                              N, out_size);
}

// Round 4
// 9870.985 us; speedup vs baseline: 1.5638x; 1.1707x over previous
//
#include <hip/hip_runtime.h>
#include <math.h>

#define DD 256
#define KK 512
#define TM 128
#define TKC 128
#define NCHUNK 4
#define DSL 32
#define NSL 8
#define NSLICES 32
#define SPLIT 4

typedef float float4v __attribute__((ext_vector_type(4)));

__device__ __forceinline__ void gld_lds16(const void* g, void* l) {
    __builtin_amdgcn_global_load_lds((const __attribute__((address_space(1))) void*)g,
                                     (__attribute__((address_space(3))) void*)l, 16, 0, 0);
}

// ---------------------------------------------------------------------------
// argmin over K=512 centroids for a 128-point block.
// Round-4: R1 structure (dbuf 64KB, launch_bounds(256,2), 128 VGPR verified)
// + counted-vmcnt pipeline (T3/T4, m201 pattern): raw s_barrier instead of
// __syncthreads (which drains vmcnt(0) and exposes stage latency every
// slice), prefetch depth 2, each wave waits only its own 8 stage loads
// (vmcnt(8)) leaving the next slice's 8 in flight across the barrier.
// R2/R3 lesson: do NOT restructure the loop shell (single-buffer variants
// made the allocator spill acc -> 15-24GB scratch traffic).  This keeps the
// R1 shell byte-compatible except barrier/waitcnt and STAGE depth.
// ---------------------------------------------------------------------------
__global__ __launch_bounds__(256, 2)
void argmin_kernel(const float* __restrict__ x, const float* __restrict__ cent,
                   const float* __restrict__ xx, const float* __restrict__ cc,
                   const int N,
                   int* __restrict__ assign_out,
                   const int* __restrict__ prev, const int pstride,
                   unsigned int* __restrict__ mismatch)
{
    __shared__ float xs[2][TM * DSL];   // 2 x 16 KB
    __shared__ float cs[2][TKC * DSL];  // 2 x 16 KB

    const int tid  = threadIdx.x;
    const int w    = tid >> 6;
    const int lane = tid & 63;
    const int tr   = tid >> 4;   // 0..15 (point dim)
    const int tc   = tid & 15;   // 0..15 (centroid dim)
    const long long rowbase = (long long)blockIdx.x * TM;

    float minv[8]; int mini[8]; float xxr[8];
#pragma unroll
    for (int i = 0; i < 8; ++i) {
        minv[i] = __builtin_inff(); mini[i] = 0;
        int r = ((i >> 2) << 6) + (tr << 2) + (i & 3);
        long long p = rowbase + r; if (p > N - 1) p = N - 1;
        xxr[i] = xx[p];
    }

    const int r_st  = (w << 3) + (lane >> 3);
    const int slot4 = (lane & 7) << 2;

    // 8 global_load_lds per thread per STAGE (4 calls x {x, cent})
#define STAGE(BUF, S) do {                                                        \
        const int d0_    = ((S) & 7) * DSL;                                       \
        const int cbase_ = ((S) >> 3) * TKC;                                      \
        _Pragma("unroll")                                                         \
        for (int call = 0; call < 4; ++call) {                                    \
            int r  = (call << 5) + r_st;                                          \
            int dl = slot4 ^ (((r >> 2) & 7) << 2);                               \
            long long p = rowbase + r; if (p > N - 1) p = N - 1;                  \
            gld_lds16(x + p * DD + d0_ + dl, &xs[(BUF)][((call << 2) + w) << 8]); \
            gld_lds16(cent + (long long)(cbase_ + r) * DD + d0_ + dl,             \
                      &cs[(BUF)][((call << 2) + w) << 8]);                        \
        }                                                                         \
    } while (0)

    STAGE(0, 0);
    STAGE(1, 1);
    int s = 0;
    float acc[8][8];

#pragma unroll 1
    for (int chunk = 0; chunk < NCHUNK; ++chunk) {
        float ccr[8];
#pragma unroll
        for (int j = 0; j < 8; ++j) {
            int r = ((j >> 2) << 6) + (tc << 2) + (j & 3);
            ccr[j] = cc[chunk * TKC + r];
        }
#pragma unroll
        for (int i = 0; i < 8; ++i)
#pragma unroll
            for (int j = 0; j < 8; ++j) acc[i][j] = 0.0f;

#pragma unroll 1
        for (int sl = 0; sl < NSL; ++sl) {
            const int buf = s & 1;
            // wait for STAGE(s)'s 8 loads only; STAGE(s+1)'s 8 stay in flight
            if (s < NSLICES - 1) asm volatile("s_waitcnt vmcnt(8)" ::: "memory");
            else                 asm volatile("s_waitcnt vmcnt(0)" ::: "memory");
            __builtin_amdgcn_s_barrier();     // all waves: slice s visible
#pragma unroll
            for (int g = 0; g < 8; ++g) {
                const int dl = g << 2;
                float4v ax[8], bc[8];
#pragma unroll
                for (int i = 0; i < 8; ++i) {
                    int r = ((i >> 2) << 6) + (tr << 2) + (i & 3);
                    ax[i] = *(const float4v*)&xs[buf][(r << 5) + (dl ^ (((r >> 2) & 7) << 2))];
                }
#pragma unroll
                for (int j = 0; j < 8; ++j) {
                    int r = ((j >> 2) << 6) + (tc << 2) + (j & 3);
                    bc[j] = *(const float4v*)&cs[buf][(r << 5) + (dl ^ (((r >> 2) & 7) << 2))];
                }
#pragma unroll
                for (int i = 0; i < 8; ++i)
#pragma unroll
                    for (int j = 0; j < 8; ++j) {
                        float t = acc[i][j];
                        t = fmaf(ax[i][0], bc[j][0], t);
                        t = fmaf(ax[i][1], bc[j][1], t);
                        t = fmaf(ax[i][2], bc[j][2], t);
                        t = fmaf(ax[i][3], bc[j][3], t);
                        acc[i][j] = t;
                    }
            }
            __builtin_amdgcn_s_barrier();     // all waves done reading buf
            if (s + 2 < NSLICES) STAGE(buf, s + 2);   // (s+2)&1 == buf
            ++s;
        }
        // fold this chunk into running min (registers only) — overlaps the
        // in-flight staging of the next two slices
        {
#pragma clang fp contract(off)
#pragma unroll
            for (int i = 0; i < 8; ++i)
#pragma unroll
                for (int j = 0; j < 8; ++j) {
                    int r = ((j >> 2) << 6) + (tc << 2) + (j & 3);
                    float t    = xxr[i] + ccr[j];
                    float d2   = t - 2.0f * acc[i][j];
                    float dist = sqrtf(fmaxf(d2, 0.0f));
                    if (dist < minv[i]) { minv[i] = dist; mini[i] = chunk * TKC + r; }
                }
        }
    }
#undef STAGE

    // reduce across the 16 tc lanes (bits 0..3 of lane), first-min tie-break
#pragma unroll
    for (int i = 0; i < 8; ++i) {
#pragma unroll
        for (int off = 1; off < 16; off <<= 1) {
            float ov = __shfl_xor(minv[i], off);
            int   oi = __shfl_xor(mini[i], off);
            if (ov < minv[i] || (ov == minv[i] && oi < mini[i])) { minv[i] = ov; mini[i] = oi; }
        }
    }
    if (tc == 0) {
        unsigned int mis = 0;
#pragma unroll
        for (int i = 0; i < 8; ++i) {
            long long p = rowbase + ((i >> 2) << 6) + (tr << 2) + (i & 3);
            if (p < N) {
                assign_out[p] = mini[i];
                if (prev != nullptr && prev[p * pstride] != mini[i]) ++mis;
            }
        }
        if (mis) atomicAdd(mismatch, mis);
    }
}

// row-wise squared norms (one wave per row, 256 cols)
__global__ void sqnorm_kernel(const float* __restrict__ m, float* __restrict__ out, const int n)
{
    const int w = threadIdx.x >> 6, lane = threadIdx.x & 63;
    const int row = (blockIdx.x << 2) + w;
    if (row >= n) return;
    const float4v v = *(const float4v*)&m[(long long)row * DD + (lane << 2)];
    float s = v[0]*v[0] + v[1]*v[1] + v[2]*v[2] + v[3]*v[3];
#pragma unroll
    for (int off = 1; off < 64; off <<= 1) s += __shfl_xor(s, off);
    if (lane == 0) out[row] = s;
}

// ---------------------------------------------------------------------------
// Segment-sum via counting sort + gather (replaces the 25.6M-atomic accum).
// Q40 fixed-point accumulation is order-independent => deterministic.
// ---------------------------------------------------------------------------
__global__ void hist_kernel(const int* __restrict__ assign, int* __restrict__ counts, const int N)
{
    const int p = blockIdx.x * 256 + threadIdx.x;
    if (p < N) atomicAdd(&counts[assign[p]], 1);
}

__global__ __launch_bounds__(KK)
void scan_kernel(const int* __restrict__ counts, int* __restrict__ starts, int* __restrict__ cursor)
{
    __shared__ int buf[2][KK];
    const int t = threadIdx.x;
    const int v = counts[t];
    buf[0][t] = v;
    __syncthreads();
    int src = 0;
#pragma unroll
    for (int off = 1; off < KK; off <<= 1) {
        int val = buf[src][t];
        if (t >= off) val += buf[src][t - off];
        buf[src ^ 1][t] = val;
        src ^= 1;
        __syncthreads();
    }
    const int excl = buf[src][t] - v;
    starts[t] = excl;
    cursor[t] = excl;
}

__global__ void scatter_kernel(const int* __restrict__ assign, int* __restrict__ cursor,
                               int* __restrict__ idx, const int N)
{
    const int p = blockIdx.x * 256 + threadIdx.x;
    if (p >= N) return;
    const int a = assign[p];
    const int pos = atomicAdd(&cursor[a], 1);
    idx[pos] = p;
}

__global__ __launch_bounds__(256)
void gather_kernel(const float* __restrict__ x, const int* __restrict__ idx,
                   const int* __restrict__ starts, const int* __restrict__ counts,
                   unsigned long long* __restrict__ sums)
{
    const int c    = blockIdx.x / SPLIT;
    const int part = blockIdx.x % SPLIT;
    const int d    = threadIdx.x;
    const int start = starts[c], cnt = counts[c];
    const int chunk = (cnt + SPLIT - 1) / SPLIT;
    const int i0 = part * chunk;
    int i1 = i0 + chunk; if (i1 > cnt) i1 = cnt;
    if (i1 <= i0) return;

    long long acc = 0;
    int i = i0;
    for (; i + 4 <= i1; i += 4) {
        const int p0 = idx[start + i + 0];
        const int p1 = idx[start + i + 1];
        const int p2 = idx[start + i + 2];
        const int p3 = idx[start + i + 3];
        const float v0 = x[(long long)p0 * DD + d];
        const float v1 = x[(long long)p1 * DD + d];
        const float v2 = x[(long long)p2 * DD + d];
        const float v3 = x[(long long)p3 * DD + d];
        acc += __double2ll_rn((double)v0 * 1099511627776.0);   // 2^40
        acc += __double2ll_rn((double)v1 * 1099511627776.0);
        acc += __double2ll_rn((double)v2 * 1099511627776.0);
        acc += __double2ll_rn((double)v3 * 1099511627776.0);
    }
    for (; i < i1; ++i) {
        const int p = idx[start + i];
        acc += __double2ll_rn((double)x[(long long)p * DD + d] * 1099511627776.0);
    }
    atomicAdd(&sums[(size_t)c * DD + d], (unsigned long long)acc);
}

// EMA update + squared norms of updated centroids
__global__ void update_kernel(const float* __restrict__ cent,
                              const unsigned long long* __restrict__ sums,
                              const int* __restrict__ counts,
                              float* __restrict__ updated, float* __restrict__ cc2)
{
    const int c = blockIdx.x, d = threadIdx.x;
    const int w = d >> 6, lane = d & 63;
    __shared__ float red[4];
    float u;
    {
#pragma clang fp contract(off)
        const float cnt = (float)counts[c];
        const float sf  = (float)((double)(long long)sums[(size_t)c * DD + d] * (1.0 / 1099511627776.0));
        const float nc  = sf / cnt;
        u = 0.01f * cent[(size_t)c * DD + d] + 0.99f * nc;
    }
    updated[(size_t)c * DD + d] = u;
    float s = u * u;
#pragma unroll
    for (int off = 1; off < 64; off <<= 1) s += __shfl_xor(s, off);
    if (lane == 0) red[w] = s;
    __syncthreads();
    if (d == 0) cc2[c] = (red[0] + red[1]) + (red[2] + red[3]);
}

// final select per match flag; everything emitted as f32
__global__ void output_kernel(const unsigned int* __restrict__ mismatch,
                              const int* __restrict__ a1, const int* __restrict__ a2,
                              const float* __restrict__ cent, const float* __restrict__ updated,
                              float* __restrict__ out, const int N, const int total)
{
    const int g = blockIdx.x * 256 + threadIdx.x;
    if (g >= total) return;
    const bool match = (*mismatch == 0u);
    if (g < N)       out[g] = (float)(match ? a2[g] : a1[g]);
    else if (g == N) out[g] = match ? 1.0f : 0.0f;
    else {
        const int e = g - N - 1;
        out[g] = match ? updated[e] : cent[e];
    }
}

extern "C" void kernel_launch(void* const* d_in, const int* in_sizes, int n_in,
                              void* d_out, int out_size, void* d_ws, size_t ws_size,
                              hipStream_t stream)
{
    const float* x    = (const float*)d_in[0];
    const float* cent = (const float*)d_in[1];
    const int*   prev = (const int*)d_in[2];
    const int N = in_sizes[0] / DD;
    const int pstride = (n_in >= 3 && in_sizes[2] >= 2 * N) ? 2 : 1;  // int64 defensive

    char* ws = (char*)d_ws;
    size_t off = 0;
    auto alloc = [&](size_t b) { void* p = ws + off; off += (b + 255) & ~(size_t)255; return p; };
    int*   assign1 = (int*)alloc((size_t)N * 4);
    int*   assign2 = (int*)alloc((size_t)N * 4);
    float* xx      = (float*)alloc((size_t)N * 4);
    float* cc      = (float*)alloc(KK * 4);
    float* cc2v    = (float*)alloc(KK * 4);
    int*   counts  = (int*)alloc(KK * 4);
    int*   starts  = (int*)alloc(KK * 4);
    int*   cursor  = (int*)alloc(KK * 4);
    int*   idx     = (int*)alloc((size_t)N * 4);
    unsigned long long* sums = (unsigned long long*)alloc((size_t)KK * DD * 8);
    float* updated = (float*)alloc((size_t)KK * DD * 4);
    unsigned int* mismatch = (unsigned int*)alloc(256);

    hipMemsetAsync(counts, 0, KK * 4, stream);
    hipMemsetAsync(sums, 0, (size_t)KK * DD * 8, stream);
    hipMemsetAsync(mismatch, 0, 4, stream);

    sqnorm_kernel<<<(N + 3) / 4, 256, 0, stream>>>(x, xx, N);
    sqnorm_kernel<<<(KK + 3) / 4, 256, 0, stream>>>(cent, cc, KK);

    const int gb = (N + TM - 1) / TM;
    argmin_kernel<<<gb, 256, 0, stream>>>(x, cent, xx, cc, N, assign1, prev, pstride, mismatch);

    // counting-sort + gather segment sum (replaces atomic accum_kernel)
    hist_kernel<<<(N + 255) / 256, 256, 0, stream>>>(assign1, counts, N);
    scan_kernel<<<1, KK, 0, stream>>>(counts, starts, cursor);
    scatter_kernel<<<(N + 255) / 256, 256, 0, stream>>>(assign1, cursor, idx, N);
    gather_kernel<<<KK * SPLIT, 256, 0, stream>>>(x, idx, starts, counts, sums);

    update_kernel<<<KK, 256, 0, stream>>>(cent, sums, counts, updated, cc2v);

    argmin_kernel<<<gb, 256, 0, stream>>>(x, updated, xx, cc2v, N, assign2, nullptr, 1, nullptr);

    output_kernel<<<(out_size + 255) / 256, 256, 0, stream>>>(mismatch, assign1, assign2,
                                                              cent, updated, (float*)d_out,
                                                              N, out_size);
}

// Round 5
// 1654.560 us; speedup vs baseline: 9.3295x; 5.9659x over previous
//
#include <hip/hip_runtime.h>
#include <math.h>

#define DD 256
#define KK 512
#define TM 128
#define TKC 128
#define NCHUNK 4
#define DSL 32
#define NSL 8
#define NSLICES 32
#define SPLIT 4

typedef float float4v __attribute__((ext_vector_type(4)));

__device__ __forceinline__ void gld_lds16(const void* g, void* l) {
    __builtin_amdgcn_global_load_lds((const __attribute__((address_space(1))) void*)g,
                                     (__attribute__((address_space(3))) void*)l, 16, 0, 0);
}

// ---------------------------------------------------------------------------
// argmin over K=512 centroids for a 128-point block.
// Round-5: byte-exact R1 shell (dbuf 64KB, STAGE at slice-loop TOP — the only
// placement that compiles without spilling acc; R3/R4 moved STAGE to the
// bottom and both spilled: 9-15GB scratch traffic).  Only change vs R1: the
// __syncthreads() (vmcnt(0) drain) is split into
//   s_barrier; STAGE(s+1); s_waitcnt vmcnt(8); s_barrier
// so each wave retires only its own STAGE(s) loads and the freshly issued
// STAGE(s+1) stays in flight across the compute (m201 counted-vmcnt pattern).
// NO-SPILL GATE for this kernel: FETCH ~280MB, WRITE ~81MB per dispatch.
// ---------------------------------------------------------------------------
__global__ __launch_bounds__(256, 2)
void argmin_kernel(const float* __restrict__ x, const float* __restrict__ cent,
                   const float* __restrict__ xx, const float* __restrict__ cc,
                   const int N,
                   int* __restrict__ assign_out,
                   const int* __restrict__ prev, const int pstride,
                   unsigned int* __restrict__ mismatch)
{
    __shared__ float xs[2][TM * DSL];   // 2 x 16 KB
    __shared__ float cs[2][TKC * DSL];  // 2 x 16 KB

    const int tid  = threadIdx.x;
    const int w    = tid >> 6;
    const int lane = tid & 63;
    const int tr   = tid >> 4;   // 0..15 (point dim)
    const int tc   = tid & 15;   // 0..15 (centroid dim)
    const long long rowbase = (long long)blockIdx.x * TM;

    float minv[8]; int mini[8]; float xxr[8];
#pragma unroll
    for (int i = 0; i < 8; ++i) {
        minv[i] = __builtin_inff(); mini[i] = 0;
        int r = ((i >> 2) << 6) + (tr << 2) + (i & 3);
        long long p = rowbase + r; if (p > N - 1) p = N - 1;
        xxr[i] = xx[p];
    }

    const int r_st  = (w << 3) + (lane >> 3);
    const int slot4 = (lane & 7) << 2;

    // 8 global_load_lds per thread per STAGE (4 calls x {x, cent})
#define STAGE(BUF, S) do {                                                        \
        const int d0_    = ((S) & 7) * DSL;                                       \
        const int cbase_ = ((S) >> 3) * TKC;                                      \
        _Pragma("unroll")                                                         \
        for (int call = 0; call < 4; ++call) {                                    \
            int r  = (call << 5) + r_st;                                          \
            int dl = slot4 ^ (((r >> 2) & 7) << 2);                               \
            long long p = rowbase + r; if (p > N - 1) p = N - 1;                  \
            gld_lds16(x + p * DD + d0_ + dl, &xs[(BUF)][((call << 2) + w) << 8]); \
            gld_lds16(cent + (long long)(cbase_ + r) * DD + d0_ + dl,             \
                      &cs[(BUF)][((call << 2) + w) << 8]);                        \
        }                                                                         \
    } while (0)

    STAGE(0, 0);
    int s = 0;
    float acc[8][8];

#pragma unroll 1
    for (int chunk = 0; chunk < NCHUNK; ++chunk) {
        float ccr[8];
#pragma unroll
        for (int j = 0; j < 8; ++j) {
            int r = ((j >> 2) << 6) + (tc << 2) + (j & 3);
            ccr[j] = cc[chunk * TKC + r];
        }
#pragma unroll
        for (int i = 0; i < 8; ++i)
#pragma unroll
            for (int j = 0; j < 8; ++j) acc[i][j] = 0.0f;

#pragma unroll 1
        for (int sl = 0; sl < NSL; ++sl) {
            const int buf = s & 1;
            __builtin_amdgcn_s_barrier();            // B1: all waves done reading buf^1
            if (s + 1 < NSLICES) {
                STAGE(buf ^ 1, s + 1);               // same position as R1 (no-spill shape)
                asm volatile("s_waitcnt vmcnt(8)" ::: "memory");  // retire my STAGE(s) only
            } else {
                asm volatile("s_waitcnt vmcnt(0)" ::: "memory");
            }
            __builtin_amdgcn_s_barrier();            // B2: buf fully staged for all waves
#pragma unroll
            for (int g = 0; g < 8; ++g) {
                const int dl = g << 2;
                float4v ax[8], bc[8];
#pragma unroll
                for (int i = 0; i < 8; ++i) {
                    int r = ((i >> 2) << 6) + (tr << 2) + (i & 3);
                    ax[i] = *(const float4v*)&xs[buf][(r << 5) + (dl ^ (((r >> 2) & 7) << 2))];
                }
#pragma unroll
                for (int j = 0; j < 8; ++j) {
                    int r = ((j >> 2) << 6) + (tc << 2) + (j & 3);
                    bc[j] = *(const float4v*)&cs[buf][(r << 5) + (dl ^ (((r >> 2) & 7) << 2))];
                }
#pragma unroll
                for (int i = 0; i < 8; ++i)
#pragma unroll
                    for (int j = 0; j < 8; ++j) {
                        float t = acc[i][j];
                        t = fmaf(ax[i][0], bc[j][0], t);
                        t = fmaf(ax[i][1], bc[j][1], t);
                        t = fmaf(ax[i][2], bc[j][2], t);
                        t = fmaf(ax[i][3], bc[j][3], t);
                        acc[i][j] = t;
                    }
            }
            ++s;
        }
        // fold this chunk into running min (registers only)
        {
#pragma clang fp contract(off)
#pragma unroll
            for (int i = 0; i < 8; ++i)
#pragma unroll
                for (int j = 0; j < 8; ++j) {
                    int r = ((j >> 2) << 6) + (tc << 2) + (j & 3);
                    float t    = xxr[i] + ccr[j];
                    float d2   = t - 2.0f * acc[i][j];
                    float dist = sqrtf(fmaxf(d2, 0.0f));
                    if (dist < minv[i]) { minv[i] = dist; mini[i] = chunk * TKC + r; }
                }
        }
    }
#undef STAGE

    // reduce across the 16 tc lanes (bits 0..3 of lane), first-min tie-break
#pragma unroll
    for (int i = 0; i < 8; ++i) {
#pragma unroll
        for (int off = 1; off < 16; off <<= 1) {
            float ov = __shfl_xor(minv[i], off);
            int   oi = __shfl_xor(mini[i], off);
            if (ov < minv[i] || (ov == minv[i] && oi < mini[i])) { minv[i] = ov; mini[i] = oi; }
        }
    }
    if (tc == 0) {
        unsigned int mis = 0;
#pragma unroll
        for (int i = 0; i < 8; ++i) {
            long long p = rowbase + ((i >> 2) << 6) + (tr << 2) + (i & 3);
            if (p < N) {
                assign_out[p] = mini[i];
                if (prev != nullptr && prev[p * pstride] != mini[i]) ++mis;
            }
        }
        if (mis) atomicAdd(mismatch, mis);
    }
}

// row-wise squared norms (one wave per row, 256 cols)
__global__ void sqnorm_kernel(const float* __restrict__ m, float* __restrict__ out, const int n)
{
    const int w = threadIdx.x >> 6, lane = threadIdx.x & 63;
    const int row = (blockIdx.x << 2) + w;
    if (row >= n) return;
    const float4v v = *(const float4v*)&m[(long long)row * DD + (lane << 2)];
    float s = v[0]*v[0] + v[1]*v[1] + v[2]*v[2] + v[3]*v[3];
#pragma unroll
    for (int off = 1; off < 64; off <<= 1) s += __shfl_xor(s, off);
    if (lane == 0) out[row] = s;
}

// ---------------------------------------------------------------------------
// Segment-sum via counting sort + gather (replaces the 25.6M-atomic accum).
// Q40 fixed-point accumulation is order-independent => deterministic.
// ---------------------------------------------------------------------------
__global__ void hist_kernel(const int* __restrict__ assign, int* __restrict__ counts, const int N)
{
    const int p = blockIdx.x * 256 + threadIdx.x;
    if (p < N) atomicAdd(&counts[assign[p]], 1);
}

__global__ __launch_bounds__(KK)
void scan_kernel(const int* __restrict__ counts, int* __restrict__ starts, int* __restrict__ cursor)
{
    __shared__ int buf[2][KK];
    const int t = threadIdx.x;
    const int v = counts[t];
    buf[0][t] = v;
    __syncthreads();
    int src = 0;
#pragma unroll
    for (int off = 1; off < KK; off <<= 1) {
        int val = buf[src][t];
        if (t >= off) val += buf[src][t - off];
        buf[src ^ 1][t] = val;
        src ^= 1;
        __syncthreads();
    }
    const int excl = buf[src][t] - v;
    starts[t] = excl;
    cursor[t] = excl;
}

__global__ void scatter_kernel(const int* __restrict__ assign, int* __restrict__ cursor,
                               int* __restrict__ idx, const int N)
{
    const int p = blockIdx.x * 256 + threadIdx.x;
    if (p >= N) return;
    const int a = assign[p];
    const int pos = atomicAdd(&cursor[a], 1);
    idx[pos] = p;
}

__global__ __launch_bounds__(256)
void gather_kernel(const float* __restrict__ x, const int* __restrict__ idx,
                   const int* __restrict__ starts, const int* __restrict__ counts,
                   unsigned long long* __restrict__ sums)
{
    const int c    = blockIdx.x / SPLIT;
    const int part = blockIdx.x % SPLIT;
    const int d    = threadIdx.x;
    const int start = starts[c], cnt = counts[c];
    const int chunk = (cnt + SPLIT - 1) / SPLIT;
    const int i0 = part * chunk;
    int i1 = i0 + chunk; if (i1 > cnt) i1 = cnt;
    if (i1 <= i0) return;

    long long acc = 0;
    int i = i0;
    for (; i + 4 <= i1; i += 4) {
        const int p0 = idx[start + i + 0];
        const int p1 = idx[start + i + 1];
        const int p2 = idx[start + i + 2];
        const int p3 = idx[start + i + 3];
        const float v0 = x[(long long)p0 * DD + d];
        const float v1 = x[(long long)p1 * DD + d];
        const float v2 = x[(long long)p2 * DD + d];
        const float v3 = x[(long long)p3 * DD + d];
        acc += __double2ll_rn((double)v0 * 1099511627776.0);   // 2^40
        acc += __double2ll_rn((double)v1 * 1099511627776.0);
        acc += __double2ll_rn((double)v2 * 1099511627776.0);
        acc += __double2ll_rn((double)v3 * 1099511627776.0);
    }
    for (; i < i1; ++i) {
        const int p = idx[start + i];
        acc += __double2ll_rn((double)x[(long long)p * DD + d] * 1099511627776.0);
    }
    atomicAdd(&sums[(size_t)c * DD + d], (unsigned long long)acc);
}

// EMA update + squared norms of updated centroids
__global__ void update_kernel(const float* __restrict__ cent,
                              const unsigned long long* __restrict__ sums,
                              const int* __restrict__ counts,
                              float* __restrict__ updated, float* __restrict__ cc2)
{
    const int c = blockIdx.x, d = threadIdx.x;
    const int w = d >> 6, lane = d & 63;
    __shared__ float red[4];
    float u;
    {
#pragma clang fp contract(off)
        const float cnt = (float)counts[c];
        const float sf  = (float)((double)(long long)sums[(size_t)c * DD + d] * (1.0 / 1099511627776.0));
        const float nc  = sf / cnt;
        u = 0.01f * cent[(size_t)c * DD + d] + 0.99f * nc;
    }
    updated[(size_t)c * DD + d] = u;
    float s = u * u;
#pragma unroll
    for (int off = 1; off < 64; off <<= 1) s += __shfl_xor(s, off);
    if (lane == 0) red[w] = s;
    __syncthreads();
    if (d == 0) cc2[c] = (red[0] + red[1]) + (red[2] + red[3]);
}

// final select per match flag; everything emitted as f32
__global__ void output_kernel(const unsigned int* __restrict__ mismatch,
                              const int* __restrict__ a1, const int* __restrict__ a2,
                              const float* __restrict__ cent, const float* __restrict__ updated,
                              float* __restrict__ out, const int N, const int total)
{
    const int g = blockIdx.x * 256 + threadIdx.x;
    if (g >= total) return;
    const bool match = (*mismatch == 0u);
    if (g < N)       out[g] = (float)(match ? a2[g] : a1[g]);
    else if (g == N) out[g] = match ? 1.0f : 0.0f;
    else {
        const int e = g - N - 1;
        out[g] = match ? updated[e] : cent[e];
    }
}

extern "C" void kernel_launch(void* const* d_in, const int* in_sizes, int n_in,
                              void* d_out, int out_size, void* d_ws, size_t ws_size,
                              hipStream_t stream)
{
    const float* x    = (const float*)d_in[0];
    const float* cent = (const float*)d_in[1];
    const int*   prev = (const int*)d_in[2];
    const int N = in_sizes[0] / DD;
    const int pstride = (n_in >= 3 && in_sizes[2] >= 2 * N) ? 2 : 1;  // int64 defensive

    char* ws = (char*)d_ws;
    size_t off = 0;
    auto alloc = [&](size_t b) { void* p = ws + off; off += (b + 255) & ~(size_t)255; return p; };
    int*   assign1 = (int*)alloc((size_t)N * 4);
    int*   assign2 = (int*)alloc((size_t)N * 4);
    float* xx      = (float*)alloc((size_t)N * 4);
    float* cc      = (float*)alloc(KK * 4);
    float* cc2v    = (float*)alloc(KK * 4);
    int*   counts  = (int*)alloc(KK * 4);
    int*   starts  = (int*)alloc(KK * 4);
    int*   cursor  = (int*)alloc(KK * 4);
    int*   idx     = (int*)alloc((size_t)N * 4);
    unsigned long long* sums = (unsigned long long*)alloc((size_t)KK * DD * 8);
    float* updated = (float*)alloc((size_t)KK * DD * 4);
    unsigned int* mismatch = (unsigned int*)alloc(256);

    hipMemsetAsync(counts, 0, KK * 4, stream);
    hipMemsetAsync(sums, 0, (size_t)KK * DD * 8, stream);
    hipMemsetAsync(mismatch, 0, 4, stream);

    sqnorm_kernel<<<(N + 3) / 4, 256, 0, stream>>>(x, xx, N);
    sqnorm_kernel<<<(KK + 3) / 4, 256, 0, stream>>>(cent, cc, KK);

    const int gb = (N + TM - 1) / TM;
    argmin_kernel<<<gb, 256, 0, stream>>>(x, cent, xx, cc, N, assign1, prev, pstride, mismatch);

    // counting-sort + gather segment sum (replaces atomic accum_kernel)
    hist_kernel<<<(N + 255) / 256, 256, 0, stream>>>(assign1, counts, N);
    scan_kernel<<<1, KK, 0, stream>>>(counts, starts, cursor);
    scatter_kernel<<<(N + 255) / 256, 256, 0, stream>>>(assign1, cursor, idx, N);
    gather_kernel<<<KK * SPLIT, 256, 0, stream>>>(x, idx, starts, counts, sums);

    update_kernel<<<KK, 256, 0, stream>>>(cent, sums, counts, updated, cc2v);

    argmin_kernel<<<gb, 256, 0, stream>>>(x, updated, xx, cc2v, N, assign2, nullptr, 1, nullptr);

    output_kernel<<<(out_size + 255) / 256, 256, 0, stream>>>(mismatch, assign1, assign2,
                                                              cent, updated, (float*)d_out,
                                                              N, out_size);
}

// Round 6
// 1348.353 us; speedup vs baseline: 11.4482x; 1.2271x over previous
//
#include <hip/hip_runtime.h>
#include <math.h>

#define DD 256
#define KK 512
#define TM 64
#define TKC 128
#define NCHUNK 4
#define DSL 32
#define NSL 8
#define NSLICES 32
#define SPLIT 4

typedef float float4v __attribute__((ext_vector_type(4)));

__device__ __forceinline__ void gld_lds16(const void* g, void* l) {
    __builtin_amdgcn_global_load_lds((const __attribute__((address_space(1))) void*)g,
                                     (__attribute__((address_space(3))) void*)l, 16, 0, 0);
}

// ---------------------------------------------------------------------------
// argmin over K=512 centroids for a 64-point block.
// Round-6: TM 128->64 shrinks LDS 64KB->48KB -> 3 blocks/CU (was 2).  R5
// post-mortem: vmcnt drain was NOT the stall (counted-vmcnt neutral); the
// limiter is 2 independent waves/SIMD each ~30% self-busy (no intra-wave
// read/FMA overlap possible at 128 VGPR).  3rd resident block adds a 3rd
// independent wave per SIMD.  Shell is byte-pattern R1 (single __syncthreads,
// STAGE at slice top) — the only shape the allocator compiles without
// spilling acc (R2/R3/R4 lessons).  acc[4][8]=32 regs lowers pressure.
// NO-SPILL GATE: FETCH < 500MB, WRITE < 200MB per dispatch; else revert.
// ---------------------------------------------------------------------------
__global__ __launch_bounds__(256, 2)
void argmin_kernel(const float* __restrict__ x, const float* __restrict__ cent,
                   const float* __restrict__ xx, const float* __restrict__ cc,
                   const int N,
                   int* __restrict__ assign_out,
                   const int* __restrict__ prev, const int pstride,
                   unsigned int* __restrict__ mismatch)
{
    __shared__ float xs[2][TM * DSL];   // 2 x 8 KB
    __shared__ float cs[2][TKC * DSL];  // 2 x 16 KB

    const int tid  = threadIdx.x;
    const int w    = tid >> 6;
    const int lane = tid & 63;
    const int tr   = tid >> 4;   // 0..15 (point dim: 4 rows each)
    const int tc   = tid & 15;   // 0..15 (centroid dim)
    const long long rowbase = (long long)blockIdx.x * TM;

    float minv[4]; int mini[4]; float xxr[4];
#pragma unroll
    for (int i = 0; i < 4; ++i) {
        minv[i] = __builtin_inff(); mini[i] = 0;
        int r = (tr << 2) + i;
        long long p = rowbase + r; if (p > N - 1) p = N - 1;
        xxr[i] = xx[p];
    }

    const int r_st  = (w << 3) + (lane >> 3);
    const int slot4 = (lane & 7) << 2;

    // 6 global_load_lds per thread per STAGE (4 cs calls + 2 xs calls)
#define STAGE(BUF, S) do {                                                        \
        const int d0_    = ((S) & 7) * DSL;                                       \
        const int cbase_ = ((S) >> 3) * TKC;                                      \
        _Pragma("unroll")                                                         \
        for (int call = 0; call < 4; ++call) {                                    \
            int r  = (call << 5) + r_st;                                          \
            int dl = slot4 ^ (((r >> 2) & 7) << 2);                               \
            gld_lds16(cent + (long long)(cbase_ + r) * DD + d0_ + dl,             \
                      &cs[(BUF)][((call << 2) + w) << 8]);                        \
            if (call < 2) {                                                       \
                long long p = rowbase + r; if (p > N - 1) p = N - 1;              \
                gld_lds16(x + p * DD + d0_ + dl,                                  \
                          &xs[(BUF)][((call << 2) + w) << 8]);                    \
            }                                                                     \
        }                                                                         \
    } while (0)

    STAGE(0, 0);
    int s = 0;
    float acc[4][8];

#pragma unroll 1
    for (int chunk = 0; chunk < NCHUNK; ++chunk) {
        float ccr[8];
#pragma unroll
        for (int j = 0; j < 8; ++j) {
            int r = ((j >> 2) << 6) + (tc << 2) + (j & 3);
            ccr[j] = cc[chunk * TKC + r];
        }
#pragma unroll
        for (int i = 0; i < 4; ++i)
#pragma unroll
            for (int j = 0; j < 8; ++j) acc[i][j] = 0.0f;

#pragma unroll 1
        for (int sl = 0; sl < NSL; ++sl) {
            const int buf = s & 1;
            __syncthreads();                      // compiler drains vmcnt here
            if (s + 1 < NSLICES) STAGE(buf ^ 1, s + 1);
#pragma unroll
            for (int g = 0; g < 8; ++g) {
                const int dl = g << 2;
                float4v ax[4], bc[8];
#pragma unroll
                for (int i = 0; i < 4; ++i) {
                    int r = (tr << 2) + i;
                    ax[i] = *(const float4v*)&xs[buf][(r << 5) + (dl ^ (((r >> 2) & 7) << 2))];
                }
#pragma unroll
                for (int j = 0; j < 8; ++j) {
                    int r = ((j >> 2) << 6) + (tc << 2) + (j & 3);
                    bc[j] = *(const float4v*)&cs[buf][(r << 5) + (dl ^ (((r >> 2) & 7) << 2))];
                }
#pragma unroll
                for (int i = 0; i < 4; ++i)
#pragma unroll
                    for (int j = 0; j < 8; ++j) {
                        float t = acc[i][j];
                        t = fmaf(ax[i][0], bc[j][0], t);
                        t = fmaf(ax[i][1], bc[j][1], t);
                        t = fmaf(ax[i][2], bc[j][2], t);
                        t = fmaf(ax[i][3], bc[j][3], t);
                        acc[i][j] = t;
                    }
            }
            ++s;
        }
        // fold this chunk into running min (registers only)
        {
#pragma clang fp contract(off)
#pragma unroll
            for (int i = 0; i < 4; ++i)
#pragma unroll
                for (int j = 0; j < 8; ++j) {
                    int r = ((j >> 2) << 6) + (tc << 2) + (j & 3);
                    float t    = xxr[i] + ccr[j];
                    float d2   = t - 2.0f * acc[i][j];
                    float dist = sqrtf(fmaxf(d2, 0.0f));
                    if (dist < minv[i]) { minv[i] = dist; mini[i] = chunk * TKC + r; }
                }
        }
    }
#undef STAGE

    // reduce across the 16 tc lanes (bits 0..3 of lane), first-min tie-break
#pragma unroll
    for (int i = 0; i < 4; ++i) {
#pragma unroll
        for (int off = 1; off < 16; off <<= 1) {
            float ov = __shfl_xor(minv[i], off);
            int   oi = __shfl_xor(mini[i], off);
            if (ov < minv[i] || (ov == minv[i] && oi < mini[i])) { minv[i] = ov; mini[i] = oi; }
        }
    }
    if (tc == 0) {
        unsigned int mis = 0;
#pragma unroll
        for (int i = 0; i < 4; ++i) {
            long long p = rowbase + (tr << 2) + i;
            if (p < N) {
                assign_out[p] = mini[i];
                if (prev != nullptr && prev[p * pstride] != mini[i]) ++mis;
            }
        }
        if (mis) atomicAdd(mismatch, mis);
    }
}

// row-wise squared norms (one wave per row, 256 cols)
__global__ void sqnorm_kernel(const float* __restrict__ m, float* __restrict__ out, const int n)
{
    const int w = threadIdx.x >> 6, lane = threadIdx.x & 63;
    const int row = (blockIdx.x << 2) + w;
    if (row >= n) return;
    const float4v v = *(const float4v*)&m[(long long)row * DD + (lane << 2)];
    float s = v[0]*v[0] + v[1]*v[1] + v[2]*v[2] + v[3]*v[3];
#pragma unroll
    for (int off = 1; off < 64; off <<= 1) s += __shfl_xor(s, off);
    if (lane == 0) out[row] = s;
}

// ---------------------------------------------------------------------------
// Segment-sum via counting sort + gather (replaces the 25.6M-atomic accum).
// Q40 fixed-point accumulation is order-independent => deterministic.
// ---------------------------------------------------------------------------
__global__ void hist_kernel(const int* __restrict__ assign, int* __restrict__ counts, const int N)
{
    const int p = blockIdx.x * 256 + threadIdx.x;
    if (p < N) atomicAdd(&counts[assign[p]], 1);
}

__global__ __launch_bounds__(KK)
void scan_kernel(const int* __restrict__ counts, int* __restrict__ starts, int* __restrict__ cursor)
{
    __shared__ int buf[2][KK];
    const int t = threadIdx.x;
    const int v = counts[t];
    buf[0][t] = v;
    __syncthreads();
    int src = 0;
#pragma unroll
    for (int off = 1; off < KK; off <<= 1) {
        int val = buf[src][t];
        if (t >= off) val += buf[src][t - off];
        buf[src ^ 1][t] = val;
        src ^= 1;
        __syncthreads();
    }
    const int excl = buf[src][t] - v;
    starts[t] = excl;
    cursor[t] = excl;
}

__global__ void scatter_kernel(const int* __restrict__ assign, int* __restrict__ cursor,
                               int* __restrict__ idx, const int N)
{
    const int p = blockIdx.x * 256 + threadIdx.x;
    if (p >= N) return;
    const int a = assign[p];
    const int pos = atomicAdd(&cursor[a], 1);
    idx[pos] = p;
}

__global__ __launch_bounds__(256)
void gather_kernel(const float* __restrict__ x, const int* __restrict__ idx,
                   const int* __restrict__ starts, const int* __restrict__ counts,
                   unsigned long long* __restrict__ sums)
{
    const int c    = blockIdx.x / SPLIT;
    const int part = blockIdx.x % SPLIT;
    const int d    = threadIdx.x;
    const int start = starts[c], cnt = counts[c];
    const int chunk = (cnt + SPLIT - 1) / SPLIT;
    const int i0 = part * chunk;
    int i1 = i0 + chunk; if (i1 > cnt) i1 = cnt;
    if (i1 <= i0) return;

    long long acc = 0;
    int i = i0;
    for (; i + 4 <= i1; i += 4) {
        const int p0 = idx[start + i + 0];
        const int p1 = idx[start + i + 1];
        const int p2 = idx[start + i + 2];
        const int p3 = idx[start + i + 3];
        const float v0 = x[(long long)p0 * DD + d];
        const float v1 = x[(long long)p1 * DD + d];
        const float v2 = x[(long long)p2 * DD + d];
        const float v3 = x[(long long)p3 * DD + d];
        acc += __double2ll_rn((double)v0 * 1099511627776.0);   // 2^40
        acc += __double2ll_rn((double)v1 * 1099511627776.0);
        acc += __double2ll_rn((double)v2 * 1099511627776.0);
        acc += __double2ll_rn((double)v3 * 1099511627776.0);
    }
    for (; i < i1; ++i) {
        const int p = idx[start + i];
        acc += __double2ll_rn((double)x[(long long)p * DD + d] * 1099511627776.0);
    }
    atomicAdd(&sums[(size_t)c * DD + d], (unsigned long long)acc);
}

// EMA update + squared norms of updated centroids
__global__ void update_kernel(const float* __restrict__ cent,
                              const unsigned long long* __restrict__ sums,
                              const int* __restrict__ counts,
                              float* __restrict__ updated, float* __restrict__ cc2)
{
    const int c = blockIdx.x, d = threadIdx.x;
    const int w = d >> 6, lane = d & 63;
    __shared__ float red[4];
    float u;
    {
#pragma clang fp contract(off)
        const float cnt = (float)counts[c];
        const float sf  = (float)((double)(long long)sums[(size_t)c * DD + d] * (1.0 / 1099511627776.0));
        const float nc  = sf / cnt;
        u = 0.01f * cent[(size_t)c * DD + d] + 0.99f * nc;
    }
    updated[(size_t)c * DD + d] = u;
    float s = u * u;
#pragma unroll
    for (int off = 1; off < 64; off <<= 1) s += __shfl_xor(s, off);
    if (lane == 0) red[w] = s;
    __syncthreads();
    if (d == 0) cc2[c] = (red[0] + red[1]) + (red[2] + red[3]);
}

// final select per match flag; everything emitted as f32
__global__ void output_kernel(const unsigned int* __restrict__ mismatch,
                              const int* __restrict__ a1, const int* __restrict__ a2,
                              const float* __restrict__ cent, const float* __restrict__ updated,
                              float* __restrict__ out, const int N, const int total)
{
    const int g = blockIdx.x * 256 + threadIdx.x;
    if (g >= total) return;
    const bool match = (*mismatch == 0u);
    if (g < N)       out[g] = (float)(match ? a2[g] : a1[g]);
    else if (g == N) out[g] = match ? 1.0f : 0.0f;
    else {
        const int e = g - N - 1;
        out[g] = match ? updated[e] : cent[e];
    }
}

extern "C" void kernel_launch(void* const* d_in, const int* in_sizes, int n_in,
                              void* d_out, int out_size, void* d_ws, size_t ws_size,
                              hipStream_t stream)
{
    const float* x    = (const float*)d_in[0];
    const float* cent = (const float*)d_in[1];
    const int*   prev = (const int*)d_in[2];
    const int N = in_sizes[0] / DD;
    const int pstride = (n_in >= 3 && in_sizes[2] >= 2 * N) ? 2 : 1;  // int64 defensive

    char* ws = (char*)d_ws;
    size_t off = 0;
    auto alloc = [&](size_t b) { void* p = ws + off; off += (b + 255) & ~(size_t)255; return p; };
    int*   assign1 = (int*)alloc((size_t)N * 4);
    int*   assign2 = (int*)alloc((size_t)N * 4);
    float* xx      = (float*)alloc((size_t)N * 4);
    float* cc      = (float*)alloc(KK * 4);
    float* cc2v    = (float*)alloc(KK * 4);
    int*   counts  = (int*)alloc(KK * 4);
    int*   starts  = (int*)alloc(KK * 4);
    int*   cursor  = (int*)alloc(KK * 4);
    int*   idx     = (int*)alloc((size_t)N * 4);
    unsigned long long* sums = (unsigned long long*)alloc((size_t)KK * DD * 8);
    float* updated = (float*)alloc((size_t)KK * DD * 4);
    unsigned int* mismatch = (unsigned int*)alloc(256);

    hipMemsetAsync(counts, 0, KK * 4, stream);
    hipMemsetAsync(sums, 0, (size_t)KK * DD * 8, stream);
    hipMemsetAsync(mismatch, 0, 4, stream);

    sqnorm_kernel<<<(N + 3) / 4, 256, 0, stream>>>(x, xx, N);
    sqnorm_kernel<<<(KK + 3) / 4, 256, 0, stream>>>(cent, cc, KK);

    const int gb = (N + TM - 1) / TM;
    argmin_kernel<<<gb, 256, 0, stream>>>(x, cent, xx, cc, N, assign1, prev, pstride, mismatch);

    // counting-sort + gather segment sum (replaces atomic accum_kernel)
    hist_kernel<<<(N + 255) / 256, 256, 0, stream>>>(assign1, counts, N);
    scan_kernel<<<1, KK, 0, stream>>>(counts, starts, cursor);
    scatter_kernel<<<(N + 255) / 256, 256, 0, stream>>>(assign1, cursor, idx, N);
    gather_kernel<<<KK * SPLIT, 256, 0, stream>>>(x, idx, starts, counts, sums);

    update_kernel<<<KK, 256, 0, stream>>>(cent, sums, counts, updated, cc2v);

    argmin_kernel<<<gb, 256, 0, stream>>>(x, updated, xx, cc2v, N, assign2, nullptr, 1, nullptr);

    output_kernel<<<(out_size + 255) / 256, 256, 0, stream>>>(mismatch, assign1, assign2,
                                                              cent, updated, (float*)d_out,
                                                              N, out_size);
}

// Round 7
// 1282.593 us; speedup vs baseline: 12.0351x; 1.0513x over previous
//
#include <hip/hip_runtime.h>
#include <math.h>

#define DD 256
#define KK 512
#define TM 64
#define TKC 128
#define NCHUNK 4
#define DSL 32
#define NSL 8
#define NSLICES 32
#define SPLIT 4

typedef float float4v __attribute__((ext_vector_type(4)));
typedef float float2v __attribute__((ext_vector_type(2)));

__device__ __forceinline__ void gld_lds16(const void* g, void* l) {
    __builtin_amdgcn_global_load_lds((const __attribute__((address_space(1))) void*)g,
                                     (__attribute__((address_space(3))) void*)l, 16, 0, 0);
}

// ---------------------------------------------------------------------------
// argmin over K=512 centroids for a 64-point block.
// Round-7: R6 shell kept byte-identical (TM=64, 48KB LDS, 3 blocks/CU,
// STAGE at slice top — the only allocator-proven shape).  ONLY change: the
// inner product accumulates into float2 lanes via __builtin_elementwise_fma
// so the compiler emits v_pk_fma_f32 (VOP3P, 2 FMA/instr) — VALU issue was
// the measured dominant pipe (74% busy, R6).  Two pk-FMAs per (i,j) per g
// replace four scalar v_fma_f32.  Horizontal acc2.x+acc2.y fold at chunk end.
// NO-SPILL GATE: FETCH ~170MB, WRITE ~1MB, VGPR <= 170; else revert.
// ---------------------------------------------------------------------------
__global__ __launch_bounds__(256, 2)
void argmin_kernel(const float* __restrict__ x, const float* __restrict__ cent,
                   const float* __restrict__ xx, const float* __restrict__ cc,
                   const int N,
                   int* __restrict__ assign_out,
                   const int* __restrict__ prev, const int pstride,
                   unsigned int* __restrict__ mismatch)
{
    __shared__ float xs[2][TM * DSL];   // 2 x 8 KB
    __shared__ float cs[2][TKC * DSL];  // 2 x 16 KB

    const int tid  = threadIdx.x;
    const int w    = tid >> 6;
    const int lane = tid & 63;
    const int tr   = tid >> 4;   // 0..15 (point dim: 4 rows each)
    const int tc   = tid & 15;   // 0..15 (centroid dim)
    const long long rowbase = (long long)blockIdx.x * TM;

    float minv[4]; int mini[4]; float xxr[4];
#pragma unroll
    for (int i = 0; i < 4; ++i) {
        minv[i] = __builtin_inff(); mini[i] = 0;
        int r = (tr << 2) + i;
        long long p = rowbase + r; if (p > N - 1) p = N - 1;
        xxr[i] = xx[p];
    }

    const int r_st  = (w << 3) + (lane >> 3);
    const int slot4 = (lane & 7) << 2;

    // 6 global_load_lds per thread per STAGE (4 cs calls + 2 xs calls)
#define STAGE(BUF, S) do {                                                        \
        const int d0_    = ((S) & 7) * DSL;                                       \
        const int cbase_ = ((S) >> 3) * TKC;                                      \
        _Pragma("unroll")                                                         \
        for (int call = 0; call < 4; ++call) {                                    \
            int r  = (call << 5) + r_st;                                          \
            int dl = slot4 ^ (((r >> 2) & 7) << 2);                               \
            gld_lds16(cent + (long long)(cbase_ + r) * DD + d0_ + dl,             \
                      &cs[(BUF)][((call << 2) + w) << 8]);                        \
            if (call < 2) {                                                       \
                long long p = rowbase + r; if (p > N - 1) p = N - 1;              \
                gld_lds16(x + p * DD + d0_ + dl,                                  \
                          &xs[(BUF)][((call << 2) + w) << 8]);                    \
            }                                                                     \
        }                                                                         \
    } while (0)

    STAGE(0, 0);
    int s = 0;
    float2v acc2[4][8];

#pragma unroll 1
    for (int chunk = 0; chunk < NCHUNK; ++chunk) {
        float ccr[8];
#pragma unroll
        for (int j = 0; j < 8; ++j) {
            int r = ((j >> 2) << 6) + (tc << 2) + (j & 3);
            ccr[j] = cc[chunk * TKC + r];
        }
#pragma unroll
        for (int i = 0; i < 4; ++i)
#pragma unroll
            for (int j = 0; j < 8; ++j) acc2[i][j] = (float2v){0.0f, 0.0f};

#pragma unroll 1
        for (int sl = 0; sl < NSL; ++sl) {
            const int buf = s & 1;
            __syncthreads();                      // compiler drains vmcnt here
            if (s + 1 < NSLICES) STAGE(buf ^ 1, s + 1);
#pragma unroll
            for (int g = 0; g < 8; ++g) {
                const int dl = g << 2;
                float4v ax[4], bc[8];
#pragma unroll
                for (int i = 0; i < 4; ++i) {
                    int r = (tr << 2) + i;
                    ax[i] = *(const float4v*)&xs[buf][(r << 5) + (dl ^ (((r >> 2) & 7) << 2))];
                }
#pragma unroll
                for (int j = 0; j < 8; ++j) {
                    int r = ((j >> 2) << 6) + (tc << 2) + (j & 3);
                    bc[j] = *(const float4v*)&cs[buf][(r << 5) + (dl ^ (((r >> 2) & 7) << 2))];
                }
#pragma unroll
                for (int i = 0; i < 4; ++i) {
                    const float2v axl = __builtin_shufflevector(ax[i], ax[i], 0, 1);
                    const float2v axh = __builtin_shufflevector(ax[i], ax[i], 2, 3);
#pragma unroll
                    for (int j = 0; j < 8; ++j) {
                        const float2v bcl = __builtin_shufflevector(bc[j], bc[j], 0, 1);
                        const float2v bch = __builtin_shufflevector(bc[j], bc[j], 2, 3);
                        float2v t = acc2[i][j];
                        t = __builtin_elementwise_fma(axl, bcl, t);   // v_pk_fma_f32
                        t = __builtin_elementwise_fma(axh, bch, t);   // v_pk_fma_f32
                        acc2[i][j] = t;
                    }
                }
            }
            ++s;
        }
        // fold this chunk into running min (registers only)
        {
#pragma clang fp contract(off)
#pragma unroll
            for (int i = 0; i < 4; ++i)
#pragma unroll
                for (int j = 0; j < 8; ++j) {
                    int r = ((j >> 2) << 6) + (tc << 2) + (j & 3);
                    float dot  = acc2[i][j][0] + acc2[i][j][1];
                    float t    = xxr[i] + ccr[j];
                    float d2   = t - 2.0f * dot;
                    float dist = sqrtf(fmaxf(d2, 0.0f));
                    if (dist < minv[i]) { minv[i] = dist; mini[i] = chunk * TKC + r; }
                }
        }
    }
#undef STAGE

    // reduce across the 16 tc lanes (bits 0..3 of lane), first-min tie-break
#pragma unroll
    for (int i = 0; i < 4; ++i) {
#pragma unroll
        for (int off = 1; off < 16; off <<= 1) {
            float ov = __shfl_xor(minv[i], off);
            int   oi = __shfl_xor(mini[i], off);
            if (ov < minv[i] || (ov == minv[i] && oi < mini[i])) { minv[i] = ov; mini[i] = oi; }
        }
    }
    if (tc == 0) {
        unsigned int mis = 0;
#pragma unroll
        for (int i = 0; i < 4; ++i) {
            long long p = rowbase + (tr << 2) + i;
            if (p < N) {
                assign_out[p] = mini[i];
                if (prev != nullptr && prev[p * pstride] != mini[i]) ++mis;
            }
        }
        if (mis) atomicAdd(mismatch, mis);
    }
}

// row-wise squared norms (one wave per row, 256 cols)
__global__ void sqnorm_kernel(const float* __restrict__ m, float* __restrict__ out, const int n)
{
    const int w = threadIdx.x >> 6, lane = threadIdx.x & 63;
    const int row = (blockIdx.x << 2) + w;
    if (row >= n) return;
    const float4v v = *(const float4v*)&m[(long long)row * DD + (lane << 2)];
    float s = v[0]*v[0] + v[1]*v[1] + v[2]*v[2] + v[3]*v[3];
#pragma unroll
    for (int off = 1; off < 64; off <<= 1) s += __shfl_xor(s, off);
    if (lane == 0) out[row] = s;
}

// ---------------------------------------------------------------------------
// Segment-sum via counting sort + gather (replaces the 25.6M-atomic accum).
// Q40 fixed-point accumulation is order-independent => deterministic.
// ---------------------------------------------------------------------------
__global__ void hist_kernel(const int* __restrict__ assign, int* __restrict__ counts, const int N)
{
    const int p = blockIdx.x * 256 + threadIdx.x;
    if (p < N) atomicAdd(&counts[assign[p]], 1);
}

__global__ __launch_bounds__(KK)
void scan_kernel(const int* __restrict__ counts, int* __restrict__ starts, int* __restrict__ cursor)
{
    __shared__ int buf[2][KK];
    const int t = threadIdx.x;
    const int v = counts[t];
    buf[0][t] = v;
    __syncthreads();
    int src = 0;
#pragma unroll
    for (int off = 1; off < KK; off <<= 1) {
        int val = buf[src][t];
        if (t >= off) val += buf[src][t - off];
        buf[src ^ 1][t] = val;
        src ^= 1;
        __syncthreads();
    }
    const int excl = buf[src][t] - v;
    starts[t] = excl;
    cursor[t] = excl;
}

__global__ void scatter_kernel(const int* __restrict__ assign, int* __restrict__ cursor,
                               int* __restrict__ idx, const int N)
{
    const int p = blockIdx.x * 256 + threadIdx.x;
    if (p >= N) return;
    const int a = assign[p];
    const int pos = atomicAdd(&cursor[a], 1);
    idx[pos] = p;
}

__global__ __launch_bounds__(256)
void gather_kernel(const float* __restrict__ x, const int* __restrict__ idx,
                   const int* __restrict__ starts, const int* __restrict__ counts,
                   unsigned long long* __restrict__ sums)
{
    const int c    = blockIdx.x / SPLIT;
    const int part = blockIdx.x % SPLIT;
    const int d    = threadIdx.x;
    const int start = starts[c], cnt = counts[c];
    const int chunk = (cnt + SPLIT - 1) / SPLIT;
    const int i0 = part * chunk;
    int i1 = i0 + chunk; if (i1 > cnt) i1 = cnt;
    if (i1 <= i0) return;

    long long acc = 0;
    int i = i0;
    for (; i + 4 <= i1; i += 4) {
        const int p0 = idx[start + i + 0];
        const int p1 = idx[start + i + 1];
        const int p2 = idx[start + i + 2];
        const int p3 = idx[start + i + 3];
        const float v0 = x[(long long)p0 * DD + d];
        const float v1 = x[(long long)p1 * DD + d];
        const float v2 = x[(long long)p2 * DD + d];
        const float v3 = x[(long long)p3 * DD + d];
        acc += __double2ll_rn((double)v0 * 1099511627776.0);   // 2^40
        acc += __double2ll_rn((double)v1 * 1099511627776.0);
        acc += __double2ll_rn((double)v2 * 1099511627776.0);
        acc += __double2ll_rn((double)v3 * 1099511627776.0);
    }
    for (; i < i1; ++i) {
        const int p = idx[start + i];
        acc += __double2ll_rn((double)x[(long long)p * DD + d] * 1099511627776.0);
    }
    atomicAdd(&sums[(size_t)c * DD + d], (unsigned long long)acc);
}

// EMA update + squared norms of updated centroids
__global__ void update_kernel(const float* __restrict__ cent,
                              const unsigned long long* __restrict__ sums,
                              const int* __restrict__ counts,
                              float* __restrict__ updated, float* __restrict__ cc2)
{
    const int c = blockIdx.x, d = threadIdx.x;
    const int w = d >> 6, lane = d & 63;
    __shared__ float red[4];
    float u;
    {
#pragma clang fp contract(off)
        const float cnt = (float)counts[c];
        const float sf  = (float)((double)(long long)sums[(size_t)c * DD + d] * (1.0 / 1099511627776.0));
        const float nc  = sf / cnt;
        u = 0.01f * cent[(size_t)c * DD + d] + 0.99f * nc;
    }
    updated[(size_t)c * DD + d] = u;
    float s = u * u;
#pragma unroll
    for (int off = 1; off < 64; off <<= 1) s += __shfl_xor(s, off);
    if (lane == 0) red[w] = s;
    __syncthreads();
    if (d == 0) cc2[c] = (red[0] + red[1]) + (red[2] + red[3]);
}

// final select per match flag; everything emitted as f32
__global__ void output_kernel(const unsigned int* __restrict__ mismatch,
                              const int* __restrict__ a1, const int* __restrict__ a2,
                              const float* __restrict__ cent, const float* __restrict__ updated,
                              float* __restrict__ out, const int N, const int total)
{
    const int g = blockIdx.x * 256 + threadIdx.x;
    if (g >= total) return;
    const bool match = (*mismatch == 0u);
    if (g < N)       out[g] = (float)(match ? a2[g] : a1[g]);
    else if (g == N) out[g] = match ? 1.0f : 0.0f;
    else {
        const int e = g - N - 1;
        out[g] = match ? updated[e] : cent[e];
    }
}

extern "C" void kernel_launch(void* const* d_in, const int* in_sizes, int n_in,
                              void* d_out, int out_size, void* d_ws, size_t ws_size,
                              hipStream_t stream)
{
    const float* x    = (const float*)d_in[0];
    const float* cent = (const float*)d_in[1];
    const int*   prev = (const int*)d_in[2];
    const int N = in_sizes[0] / DD;
    const int pstride = (n_in >= 3 && in_sizes[2] >= 2 * N) ? 2 : 1;  // int64 defensive

    char* ws = (char*)d_ws;
    size_t off = 0;
    auto alloc = [&](size_t b) { void* p = ws + off; off += (b + 255) & ~(size_t)255; return p; };
    int*   assign1 = (int*)alloc((size_t)N * 4);
    int*   assign2 = (int*)alloc((size_t)N * 4);
    float* xx      = (float*)alloc((size_t)N * 4);
    float* cc      = (float*)alloc(KK * 4);
    float* cc2v    = (float*)alloc(KK * 4);
    int*   counts  = (int*)alloc(KK * 4);
    int*   starts  = (int*)alloc(KK * 4);
    int*   cursor  = (int*)alloc(KK * 4);
    int*   idx     = (int*)alloc((size_t)N * 4);
    unsigned long long* sums = (unsigned long long*)alloc((size_t)KK * DD * 8);
    float* updated = (float*)alloc((size_t)KK * DD * 4);
    unsigned int* mismatch = (unsigned int*)alloc(256);

    hipMemsetAsync(counts, 0, KK * 4, stream);
    hipMemsetAsync(sums, 0, (size_t)KK * DD * 8, stream);
    hipMemsetAsync(mismatch, 0, 4, stream);

    sqnorm_kernel<<<(N + 3) / 4, 256, 0, stream>>>(x, xx, N);
    sqnorm_kernel<<<(KK + 3) / 4, 256, 0, stream>>>(cent, cc, KK);

    const int gb = (N + TM - 1) / TM;
    argmin_kernel<<<gb, 256, 0, stream>>>(x, cent, xx, cc, N, assign1, prev, pstride, mismatch);

    // counting-sort + gather segment sum (replaces atomic accum_kernel)
    hist_kernel<<<(N + 255) / 256, 256, 0, stream>>>(assign1, counts, N);
    scan_kernel<<<1, KK, 0, stream>>>(counts, starts, cursor);
    scatter_kernel<<<(N + 255) / 256, 256, 0, stream>>>(assign1, cursor, idx, N);
    gather_kernel<<<KK * SPLIT, 256, 0, stream>>>(x, idx, starts, counts, sums);

    update_kernel<<<KK, 256, 0, stream>>>(cent, sums, counts, updated, cc2v);

    argmin_kernel<<<gb, 256, 0, stream>>>(x, updated, xx, cc2v, N, assign2, nullptr, 1, nullptr);

    output_kernel<<<(out_size + 255) / 256, 256, 0, stream>>>(mismatch, assign1, assign2,
                                                              cent, updated, (float*)d_out,
                                                              N, out_size);
}

// Round 8
// 1198.389 us; speedup vs baseline: 12.8808x; 1.0703x over previous
//
#include <hip/hip_runtime.h>
#include <math.h>

#define DD 256
#define KK 512
#define TM 64
#define TKC 128
#define NCHUNK 4
#define DSL 32
#define NSL 8
#define NSLICES 32
#define SPLIT 4

typedef float float4v __attribute__((ext_vector_type(4)));
typedef float float2v __attribute__((ext_vector_type(2)));

__device__ __forceinline__ void gld_lds16(const void* g, void* l) {
    __builtin_amdgcn_global_load_lds((const __attribute__((address_space(1))) void*)g,
                                     (__attribute__((address_space(3))) void*)l, 16, 0, 0);
}

// ---------------------------------------------------------------------------
// argmin over K=512 centroids for a 64-point block.
// Round-8: main loop byte-identical to R7 (TM=64, 48KB LDS, 3 blocks/CU,
// pk_fma core — allocator-proven).  Fusions OUTSIDE the fragile loop only:
//  * prologue computes row norms in-kernel (xx is argmin-invariant: per-row
//    constant under monotone ops — any consistent value gives identical
//    assignments).  Pass1 writes xx[p] for pass2; sqnorm_x kernel deleted.
//  * pass1 epilogue fuses hist (atomicAdd counts) — hist kernel deleted.
// NO-SPILL GATE: FETCH ~170MB, WRITE ~1MB, VGPR <= 130; else revert.
// ---------------------------------------------------------------------------
template<bool FIRST>
__global__ __launch_bounds__(256, 2)
void argmin_kernel(const float* __restrict__ x, const float* __restrict__ cent,
                   float* __restrict__ xx, const float* __restrict__ cc,
                   const int N,
                   int* __restrict__ assign_out,
                   const int* __restrict__ prev, const int pstride,
                   unsigned int* __restrict__ mismatch,
                   int* __restrict__ counts)
{
    __shared__ float xs[2][TM * DSL];   // 2 x 8 KB
    __shared__ float cs[2][TKC * DSL];  // 2 x 16 KB

    const int tid  = threadIdx.x;
    const int w    = tid >> 6;
    const int lane = tid & 63;
    const int tr   = tid >> 4;   // 0..15 (point dim: 4 rows each)
    const int tc   = tid & 15;   // 0..15 (centroid dim)
    const long long rowbase = (long long)blockIdx.x * TM;

    float minv[4]; int mini[4]; float xxr[4];
#pragma unroll
    for (int i = 0; i < 4; ++i) { minv[i] = __builtin_inff(); mini[i] = 0; }

    if (FIRST) {
        // in-kernel row norms: thread reads its 4 rows' 16-float tc-slice,
        // squares, reduces across the 16 tc lanes.  Also warms L2 for staging.
#pragma unroll
        for (int i = 0; i < 4; ++i) {
            long long p = rowbase + (tr << 2) + i; if (p > N - 1) p = N - 1;
            const float4v* xr = (const float4v*)&x[p * DD + (tc << 4)];
            float s = 0.0f;
#pragma unroll
            for (int q = 0; q < 4; ++q) {
                const float4v v = xr[q];
                s += v[0]*v[0] + v[1]*v[1] + v[2]*v[2] + v[3]*v[3];
            }
#pragma unroll
            for (int off = 1; off < 16; off <<= 1) s += __shfl_xor(s, off);
            xxr[i] = s;
        }
    } else {
#pragma unroll
        for (int i = 0; i < 4; ++i) {
            long long p = rowbase + (tr << 2) + i; if (p > N - 1) p = N - 1;
            xxr[i] = xx[p];
        }
    }

    const int r_st  = (w << 3) + (lane >> 3);
    const int slot4 = (lane & 7) << 2;

    // 6 global_load_lds per thread per STAGE (4 cs calls + 2 xs calls)
#define STAGE(BUF, S) do {                                                        \
        const int d0_    = ((S) & 7) * DSL;                                       \
        const int cbase_ = ((S) >> 3) * TKC;                                      \
        _Pragma("unroll")                                                         \
        for (int call = 0; call < 4; ++call) {                                    \
            int r  = (call << 5) + r_st;                                          \
            int dl = slot4 ^ (((r >> 2) & 7) << 2);                               \
            gld_lds16(cent + (long long)(cbase_ + r) * DD + d0_ + dl,             \
                      &cs[(BUF)][((call << 2) + w) << 8]);                        \
            if (call < 2) {                                                       \
                long long p = rowbase + r; if (p > N - 1) p = N - 1;              \
                gld_lds16(x + p * DD + d0_ + dl,                                  \
                          &xs[(BUF)][((call << 2) + w) << 8]);                    \
            }                                                                     \
        }                                                                         \
    } while (0)

    STAGE(0, 0);
    int s = 0;
    float2v acc2[4][8];

#pragma unroll 1
    for (int chunk = 0; chunk < NCHUNK; ++chunk) {
        float ccr[8];
#pragma unroll
        for (int j = 0; j < 8; ++j) {
            int r = ((j >> 2) << 6) + (tc << 2) + (j & 3);
            ccr[j] = cc[chunk * TKC + r];
        }
#pragma unroll
        for (int i = 0; i < 4; ++i)
#pragma unroll
            for (int j = 0; j < 8; ++j) acc2[i][j] = (float2v){0.0f, 0.0f};

#pragma unroll 1
        for (int sl = 0; sl < NSL; ++sl) {
            const int buf = s & 1;
            __syncthreads();                      // compiler drains vmcnt here
            if (s + 1 < NSLICES) STAGE(buf ^ 1, s + 1);
#pragma unroll
            for (int g = 0; g < 8; ++g) {
                const int dl = g << 2;
                float4v ax[4], bc[8];
#pragma unroll
                for (int i = 0; i < 4; ++i) {
                    int r = (tr << 2) + i;
                    ax[i] = *(const float4v*)&xs[buf][(r << 5) + (dl ^ (((r >> 2) & 7) << 2))];
                }
#pragma unroll
                for (int j = 0; j < 8; ++j) {
                    int r = ((j >> 2) << 6) + (tc << 2) + (j & 3);
                    bc[j] = *(const float4v*)&cs[buf][(r << 5) + (dl ^ (((r >> 2) & 7) << 2))];
                }
#pragma unroll
                for (int i = 0; i < 4; ++i) {
                    const float2v axl = __builtin_shufflevector(ax[i], ax[i], 0, 1);
                    const float2v axh = __builtin_shufflevector(ax[i], ax[i], 2, 3);
#pragma unroll
                    for (int j = 0; j < 8; ++j) {
                        const float2v bcl = __builtin_shufflevector(bc[j], bc[j], 0, 1);
                        const float2v bch = __builtin_shufflevector(bc[j], bc[j], 2, 3);
                        float2v t = acc2[i][j];
                        t = __builtin_elementwise_fma(axl, bcl, t);   // v_pk_fma_f32
                        t = __builtin_elementwise_fma(axh, bch, t);   // v_pk_fma_f32
                        acc2[i][j] = t;
                    }
                }
            }
            ++s;
        }
        // fold this chunk into running min (registers only)
        {
#pragma clang fp contract(off)
#pragma unroll
            for (int i = 0; i < 4; ++i)
#pragma unroll
                for (int j = 0; j < 8; ++j) {
                    int r = ((j >> 2) << 6) + (tc << 2) + (j & 3);
                    float dot  = acc2[i][j][0] + acc2[i][j][1];
                    float t    = xxr[i] + ccr[j];
                    float d2   = t - 2.0f * dot;
                    float dist = sqrtf(fmaxf(d2, 0.0f));
                    if (dist < minv[i]) { minv[i] = dist; mini[i] = chunk * TKC + r; }
                }
        }
    }
#undef STAGE

    // reduce across the 16 tc lanes (bits 0..3 of lane), first-min tie-break
#pragma unroll
    for (int i = 0; i < 4; ++i) {
#pragma unroll
        for (int off = 1; off < 16; off <<= 1) {
            float ov = __shfl_xor(minv[i], off);
            int   oi = __shfl_xor(mini[i], off);
            if (ov < minv[i] || (ov == minv[i] && oi < mini[i])) { minv[i] = ov; mini[i] = oi; }
        }
    }
    if (tc == 0) {
        unsigned int mis = 0;
#pragma unroll
        for (int i = 0; i < 4; ++i) {
            long long p = rowbase + (tr << 2) + i;
            if (p < N) {
                assign_out[p] = mini[i];
                if (FIRST) {
                    xx[p] = xxr[i];                      // pass 2 reads this
                    atomicAdd(&counts[mini[i]], 1);      // fused hist
                }
                if (prev != nullptr && prev[p * pstride] != mini[i]) ++mis;
            }
        }
        if (mis) atomicAdd(mismatch, mis);
    }
}

// row-wise squared norms (one wave per row, 256 cols) — used for centroids only
__global__ void sqnorm_kernel(const float* __restrict__ m, float* __restrict__ out, const int n)
{
    const int w = threadIdx.x >> 6, lane = threadIdx.x & 63;
    const int row = (blockIdx.x << 2) + w;
    if (row >= n) return;
    const float4v v = *(const float4v*)&m[(long long)row * DD + (lane << 2)];
    float s = v[0]*v[0] + v[1]*v[1] + v[2]*v[2] + v[3]*v[3];
#pragma unroll
    for (int off = 1; off < 64; off <<= 1) s += __shfl_xor(s, off);
    if (lane == 0) out[row] = s;
}

// ---------------------------------------------------------------------------
// Segment-sum via counting sort + gather.
// Q40 fixed-point accumulation is order-independent => deterministic.
// (hist is fused into argmin pass 1's epilogue.)
// ---------------------------------------------------------------------------
__global__ __launch_bounds__(KK)
void scan_kernel(const int* __restrict__ counts, int* __restrict__ starts, int* __restrict__ cursor)
{
    __shared__ int buf[2][KK];
    const int t = threadIdx.x;
    const int v = counts[t];
    buf[0][t] = v;
    __syncthreads();
    int src = 0;
#pragma unroll
    for (int off = 1; off < KK; off <<= 1) {
        int val = buf[src][t];
        if (t >= off) val += buf[src][t - off];
        buf[src ^ 1][t] = val;
        src ^= 1;
        __syncthreads();
    }
    const int excl = buf[src][t] - v;
    starts[t] = excl;
    cursor[t] = excl;
}

__global__ void scatter_kernel(const int* __restrict__ assign, int* __restrict__ cursor,
                               int* __restrict__ idx, const int N)
{
    const int p = blockIdx.x * 256 + threadIdx.x;
    if (p >= N) return;
    const int a = assign[p];
    const int pos = atomicAdd(&cursor[a], 1);
    idx[pos] = p;
}

__global__ __launch_bounds__(256)
void gather_kernel(const float* __restrict__ x, const int* __restrict__ idx,
                   const int* __restrict__ starts, const int* __restrict__ counts,
                   unsigned long long* __restrict__ sums)
{
    const int c    = blockIdx.x / SPLIT;
    const int part = blockIdx.x % SPLIT;
    const int d    = threadIdx.x;
    const int start = starts[c], cnt = counts[c];
    const int chunk = (cnt + SPLIT - 1) / SPLIT;
    const int i0 = part * chunk;
    int i1 = i0 + chunk; if (i1 > cnt) i1 = cnt;
    if (i1 <= i0) return;

    long long acc = 0;
    int i = i0;
    for (; i + 4 <= i1; i += 4) {
        const int p0 = idx[start + i + 0];
        const int p1 = idx[start + i + 1];
        const int p2 = idx[start + i + 2];
        const int p3 = idx[start + i + 3];
        const float v0 = x[(long long)p0 * DD + d];
        const float v1 = x[(long long)p1 * DD + d];
        const float v2 = x[(long long)p2 * DD + d];
        const float v3 = x[(long long)p3 * DD + d];
        acc += __double2ll_rn((double)v0 * 1099511627776.0);   // 2^40
        acc += __double2ll_rn((double)v1 * 1099511627776.0);
        acc += __double2ll_rn((double)v2 * 1099511627776.0);
        acc += __double2ll_rn((double)v3 * 1099511627776.0);
    }
    for (; i < i1; ++i) {
        const int p = idx[start + i];
        acc += __double2ll_rn((double)x[(long long)p * DD + d] * 1099511627776.0);
    }
    atomicAdd(&sums[(size_t)c * DD + d], (unsigned long long)acc);
}

// EMA update + squared norms of updated centroids
__global__ void update_kernel(const float* __restrict__ cent,
                              const unsigned long long* __restrict__ sums,
                              const int* __restrict__ counts,
                              float* __restrict__ updated, float* __restrict__ cc2)
{
    const int c = blockIdx.x, d = threadIdx.x;
    const int w = d >> 6, lane = d & 63;
    __shared__ float red[4];
    float u;
    {
#pragma clang fp contract(off)
        const float cnt = (float)counts[c];
        const float sf  = (float)((double)(long long)sums[(size_t)c * DD + d] * (1.0 / 1099511627776.0));
        const float nc  = sf / cnt;
        u = 0.01f * cent[(size_t)c * DD + d] + 0.99f * nc;
    }
    updated[(size_t)c * DD + d] = u;
    float s = u * u;
#pragma unroll
    for (int off = 1; off < 64; off <<= 1) s += __shfl_xor(s, off);
    if (lane == 0) red[w] = s;
    __syncthreads();
    if (d == 0) cc2[c] = (red[0] + red[1]) + (red[2] + red[3]);
}

// final select per match flag; everything emitted as f32
__global__ void output_kernel(const unsigned int* __restrict__ mismatch,
                              const int* __restrict__ a1, const int* __restrict__ a2,
                              const float* __restrict__ cent, const float* __restrict__ updated,
                              float* __restrict__ out, const int N, const int total)
{
    const int g = blockIdx.x * 256 + threadIdx.x;
    if (g >= total) return;
    const bool match = (*mismatch == 0u);
    if (g < N)       out[g] = (float)(match ? a2[g] : a1[g]);
    else if (g == N) out[g] = match ? 1.0f : 0.0f;
    else {
        const int e = g - N - 1;
        out[g] = match ? updated[e] : cent[e];
    }
}

extern "C" void kernel_launch(void* const* d_in, const int* in_sizes, int n_in,
                              void* d_out, int out_size, void* d_ws, size_t ws_size,
                              hipStream_t stream)
{
    const float* x    = (const float*)d_in[0];
    const float* cent = (const float*)d_in[1];
    const int*   prev = (const int*)d_in[2];
    const int N = in_sizes[0] / DD;
    const int pstride = (n_in >= 3 && in_sizes[2] >= 2 * N) ? 2 : 1;  // int64 defensive

    char* ws = (char*)d_ws;
    size_t off = 0;
    auto alloc = [&](size_t b) { void* p = ws + off; off += (b + 255) & ~(size_t)255; return p; };
    int*   assign1 = (int*)alloc((size_t)N * 4);
    int*   assign2 = (int*)alloc((size_t)N * 4);
    float* xx      = (float*)alloc((size_t)N * 4);
    float* cc      = (float*)alloc(KK * 4);
    float* cc2v    = (float*)alloc(KK * 4);
    int*   counts  = (int*)alloc(KK * 4);
    int*   starts  = (int*)alloc(KK * 4);
    int*   cursor  = (int*)alloc(KK * 4);
    int*   idx     = (int*)alloc((size_t)N * 4);
    unsigned long long* sums = (unsigned long long*)alloc((size_t)KK * DD * 8);
    float* updated = (float*)alloc((size_t)KK * DD * 4);
    unsigned int* mismatch = (unsigned int*)alloc(256);

    hipMemsetAsync(counts, 0, KK * 4, stream);
    hipMemsetAsync(sums, 0, (size_t)KK * DD * 8, stream);
    hipMemsetAsync(mismatch, 0, 4, stream);

    sqnorm_kernel<<<(KK + 3) / 4, 256, 0, stream>>>(cent, cc, KK);

    const int gb = (N + TM - 1) / TM;
    argmin_kernel<true><<<gb, 256, 0, stream>>>(x, cent, xx, cc, N, assign1,
                                                prev, pstride, mismatch, counts);

    // counting-sort + gather segment sum (hist fused into argmin pass 1)
    scan_kernel<<<1, KK, 0, stream>>>(counts, starts, cursor);
    scatter_kernel<<<(N + 255) / 256, 256, 0, stream>>>(assign1, cursor, idx, N);
    gather_kernel<<<KK * SPLIT, 256, 0, stream>>>(x, idx, starts, counts, sums);

    update_kernel<<<KK, 256, 0, stream>>>(cent, sums, counts, updated, cc2v);

    argmin_kernel<false><<<gb, 256, 0, stream>>>(x, updated, xx, cc2v, N, assign2,
                                                 nullptr, 1, nullptr, nullptr);

    output_kernel<<<(out_size + 255) / 256, 256, 0, stream>>>(mismatch, assign1, assign2,
                                                              cent, updated, (float*)d_out,
                                                              N, out_size);
}

// Round 10
// 1041.824 us; speedup vs baseline: 14.8165x; 1.1503x over previous
//
#include <hip/hip_runtime.h>
#include <math.h>

#define DD 256
#define KK 512
#define TM 64
#define TKC 128
#define NCHUNK 4
#define DSL 32
#define NSL 8
#define NSLICES 32
#define SPLIT 8

typedef float float4v __attribute__((ext_vector_type(4)));
typedef float float2v __attribute__((ext_vector_type(2)));

__device__ __forceinline__ void gld_lds16(const void* g, void* l) {
    __builtin_amdgcn_global_load_lds((const __attribute__((address_space(1))) void*)g,
                                     (__attribute__((address_space(3))) void*)l, 16, 0, 0);
}

// ---------------------------------------------------------------------------
// argmin over K=512 centroids for a 64-point block.
// Round-10: revert to the verified R8 shell (TM=64, 48KB LDS, 3 blk/CU,
// pk_fma core) after R9's 8x8 geometry composition failed correctness.
// Arithmetic-only deltas (the proven-safe class of edit for this shell):
//  * drop ||x||^2 entirely — for fixed point i, argmin_j of the distance
//    equals argmin_j (0.5*cc[j] - dot[i][j]): xx is a per-i constant under
//    a monotone map, 0.5 scale is fp-exact, and the sqrt/clamp only merge
//    ties at distance~0 (margins there are ~512, not ulp).  Deletes the
//    norm prologue, the xx buffer, and one add+sqrt per (i,j).
//  * gather SPLIT 4->8 (launch-param only).
// NO-SPILL GATE: FETCH ~170MB, WRITE ~1MB, VGPR <= 120; else revert R8.
// ---------------------------------------------------------------------------
template<bool FIRST>
__global__ __launch_bounds__(256, 2)
void argmin_kernel(const float* __restrict__ x, const float* __restrict__ cent,
                   const float* __restrict__ cc,
                   const int N,
                   int* __restrict__ assign_out,
                   const int* __restrict__ prev, const int pstride,
                   unsigned int* __restrict__ mismatch,
                   int* __restrict__ counts)
{
    __shared__ float xs[2][TM * DSL];   // 2 x 8 KB
    __shared__ float cs[2][TKC * DSL];  // 2 x 16 KB

    const int tid  = threadIdx.x;
    const int w    = tid >> 6;
    const int lane = tid & 63;
    const int tr   = tid >> 4;   // 0..15 (point dim: 4 rows each)
    const int tc   = tid & 15;   // 0..15 (centroid dim)
    const long long rowbase = (long long)blockIdx.x * TM;

    float minv[4]; int mini[4];
#pragma unroll
    for (int i = 0; i < 4; ++i) { minv[i] = __builtin_inff(); mini[i] = 0; }

    const int r_st  = (w << 3) + (lane >> 3);
    const int slot4 = (lane & 7) << 2;

    // 6 global_load_lds per thread per STAGE (4 cs calls + 2 xs calls)
#define STAGE(BUF, S) do {                                                        \
        const int d0_    = ((S) & 7) * DSL;                                       \
        const int cbase_ = ((S) >> 3) * TKC;                                      \
        _Pragma("unroll")                                                         \
        for (int call = 0; call < 4; ++call) {                                    \
            int r  = (call << 5) + r_st;                                          \
            int dl = slot4 ^ (((r >> 2) & 7) << 2);                               \
            gld_lds16(cent + (long long)(cbase_ + r) * DD + d0_ + dl,             \
                      &cs[(BUF)][((call << 2) + w) << 8]);                        \
            if (call < 2) {                                                       \
                long long p = rowbase + r; if (p > N - 1) p = N - 1;              \
                gld_lds16(x + p * DD + d0_ + dl,                                  \
                          &xs[(BUF)][((call << 2) + w) << 8]);                    \
            }                                                                     \
        }                                                                         \
    } while (0)

    STAGE(0, 0);
    int s = 0;
    float2v acc2[4][8];

#pragma unroll 1
    for (int chunk = 0; chunk < NCHUNK; ++chunk) {
        float cchalf[8];
#pragma unroll
        for (int j = 0; j < 8; ++j) {
            int r = ((j >> 2) << 6) + (tc << 2) + (j & 3);
            cchalf[j] = 0.5f * cc[chunk * TKC + r];   // exact scale
        }
#pragma unroll
        for (int i = 0; i < 4; ++i)
#pragma unroll
            for (int j = 0; j < 8; ++j) acc2[i][j] = (float2v){0.0f, 0.0f};

#pragma unroll 1
        for (int sl = 0; sl < NSL; ++sl) {
            const int buf = s & 1;
            __syncthreads();                      // compiler drains vmcnt here
            if (s + 1 < NSLICES) STAGE(buf ^ 1, s + 1);
#pragma unroll
            for (int g = 0; g < 8; ++g) {
                const int dl = g << 2;
                float4v ax[4], bc[8];
#pragma unroll
                for (int i = 0; i < 4; ++i) {
                    int r = (tr << 2) + i;
                    ax[i] = *(const float4v*)&xs[buf][(r << 5) + (dl ^ (((r >> 2) & 7) << 2))];
                }
#pragma unroll
                for (int j = 0; j < 8; ++j) {
                    int r = ((j >> 2) << 6) + (tc << 2) + (j & 3);
                    bc[j] = *(const float4v*)&cs[buf][(r << 5) + (dl ^ (((r >> 2) & 7) << 2))];
                }
#pragma unroll
                for (int i = 0; i < 4; ++i) {
                    const float2v axl = __builtin_shufflevector(ax[i], ax[i], 0, 1);
                    const float2v axh = __builtin_shufflevector(ax[i], ax[i], 2, 3);
#pragma unroll
                    for (int j = 0; j < 8; ++j) {
                        const float2v bcl = __builtin_shufflevector(bc[j], bc[j], 0, 1);
                        const float2v bch = __builtin_shufflevector(bc[j], bc[j], 2, 3);
                        float2v t = acc2[i][j];
                        t = __builtin_elementwise_fma(axl, bcl, t);   // v_pk_fma_f32
                        t = __builtin_elementwise_fma(axh, bch, t);   // v_pk_fma_f32
                        acc2[i][j] = t;
                    }
                }
            }
            ++s;
        }
        // fold this chunk into running min (registers only):
        // score = 0.5*cc - dot  (same argmin as sqrt(max(xx+cc-2dot,0)))
        {
#pragma clang fp contract(off)
#pragma unroll
            for (int i = 0; i < 4; ++i)
#pragma unroll
                for (int j = 0; j < 8; ++j) {
                    int r = ((j >> 2) << 6) + (tc << 2) + (j & 3);
                    float dot   = acc2[i][j][0] + acc2[i][j][1];
                    float score = cchalf[j] - dot;
                    if (score < minv[i]) { minv[i] = score; mini[i] = chunk * TKC + r; }
                }
        }
    }
#undef STAGE

    // reduce across the 16 tc lanes (bits 0..3 of lane), first-min tie-break
#pragma unroll
    for (int i = 0; i < 4; ++i) {
#pragma unroll
        for (int off = 1; off < 16; off <<= 1) {
            float ov = __shfl_xor(minv[i], off);
            int   oi = __shfl_xor(mini[i], off);
            if (ov < minv[i] || (ov == minv[i] && oi < mini[i])) { minv[i] = ov; mini[i] = oi; }
        }
    }
    if (tc == 0) {
        unsigned int mis = 0;
#pragma unroll
        for (int i = 0; i < 4; ++i) {
            long long p = rowbase + (tr << 2) + i;
            if (p < N) {
                assign_out[p] = mini[i];
                if (FIRST) {
                    atomicAdd(&counts[mini[i]], 1);      // fused hist
                }
                if (prev != nullptr && prev[p * pstride] != mini[i]) ++mis;
            }
        }
        if (mis) atomicAdd(mismatch, mis);
    }
}

// row-wise squared norms (one wave per row, 256 cols) — used for centroids only
__global__ void sqnorm_kernel(const float* __restrict__ m, float* __restrict__ out, const int n)
{
    const int w = threadIdx.x >> 6, lane = threadIdx.x & 63;
    const int row = (blockIdx.x << 2) + w;
    if (row >= n) return;
    const float4v v = *(const float4v*)&m[(long long)row * DD + (lane << 2)];
    float s = v[0]*v[0] + v[1]*v[1] + v[2]*v[2] + v[3]*v[3];
#pragma unroll
    for (int off = 1; off < 64; off <<= 1) s += __shfl_xor(s, off);
    if (lane == 0) out[row] = s;
}

// ---------------------------------------------------------------------------
// Segment-sum via counting sort + gather.
// Q40 fixed-point accumulation is order-independent => deterministic.
// (hist is fused into argmin pass 1's epilogue.)
// ---------------------------------------------------------------------------
__global__ __launch_bounds__(KK)
void scan_kernel(const int* __restrict__ counts, int* __restrict__ starts, int* __restrict__ cursor)
{
    __shared__ int buf[2][KK];
    const int t = threadIdx.x;
    const int v = counts[t];
    buf[0][t] = v;
    __syncthreads();
    int src = 0;
#pragma unroll
    for (int off = 1; off < KK; off <<= 1) {
        int val = buf[src][t];
        if (t >= off) val += buf[src][t - off];
        buf[src ^ 1][t] = val;
        src ^= 1;
        __syncthreads();
    }
    const int excl = buf[src][t] - v;
    starts[t] = excl;
    cursor[t] = excl;
}

__global__ void scatter_kernel(const int* __restrict__ assign, int* __restrict__ cursor,
                               int* __restrict__ idx, const int N)
{
    const int p = blockIdx.x * 256 + threadIdx.x;
    if (p >= N) return;
    const int a = assign[p];
    const int pos = atomicAdd(&cursor[a], 1);
    idx[pos] = p;
}

__global__ __launch_bounds__(256)
void gather_kernel(const float* __restrict__ x, const int* __restrict__ idx,
                   const int* __restrict__ starts, const int* __restrict__ counts,
                   unsigned long long* __restrict__ sums)
{
    const int c    = blockIdx.x / SPLIT;
    const int part = blockIdx.x % SPLIT;
    const int d    = threadIdx.x;
    const int start = starts[c], cnt = counts[c];
    const int chunk = (cnt + SPLIT - 1) / SPLIT;
    const int i0 = part * chunk;
    int i1 = i0 + chunk; if (i1 > cnt) i1 = cnt;
    if (i1 <= i0) return;

    long long acc = 0;
    int i = i0;
    for (; i + 4 <= i1; i += 4) {
        const int p0 = idx[start + i + 0];
        const int p1 = idx[start + i + 1];
        const int p2 = idx[start + i + 2];
        const int p3 = idx[start + i + 3];
        const float v0 = x[(long long)p0 * DD + d];
        const float v1 = x[(long long)p1 * DD + d];
        const float v2 = x[(long long)p2 * DD + d];
        const float v3 = x[(long long)p3 * DD + d];
        acc += __double2ll_rn((double)v0 * 1099511627776.0);   // 2^40
        acc += __double2ll_rn((double)v1 * 1099511627776.0);
        acc += __double2ll_rn((double)v2 * 1099511627776.0);
        acc += __double2ll_rn((double)v3 * 1099511627776.0);
    }
    for (; i < i1; ++i) {
        const int p = idx[start + i];
        acc += __double2ll_rn((double)x[(long long)p * DD + d] * 1099511627776.0);
    }
    atomicAdd(&sums[(size_t)c * DD + d], (unsigned long long)acc);
}

// EMA update + squared norms of updated centroids
__global__ void update_kernel(const float* __restrict__ cent,
                              const unsigned long long* __restrict__ sums,
                              const int* __restrict__ counts,
                              float* __restrict__ updated, float* __restrict__ cc2)
{
    const int c = blockIdx.x, d = threadIdx.x;
    const int w = d >> 6, lane = d & 63;
    __shared__ float red[4];
    float u;
    {
#pragma clang fp contract(off)
        const float cnt = (float)counts[c];
        const float sf  = (float)((double)(long long)sums[(size_t)c * DD + d] * (1.0 / 1099511627776.0));
        const float nc  = sf / cnt;
        u = 0.01f * cent[(size_t)c * DD + d] + 0.99f * nc;
    }
    updated[(size_t)c * DD + d] = u;
    float s = u * u;
#pragma unroll
    for (int off = 1; off < 64; off <<= 1) s += __shfl_xor(s, off);
    if (lane == 0) red[w] = s;
    __syncthreads();
    if (d == 0) cc2[c] = (red[0] + red[1]) + (red[2] + red[3]);
}

// final select per match flag; everything emitted as f32
__global__ void output_kernel(const unsigned int* __restrict__ mismatch,
                              const int* __restrict__ a1, const int* __restrict__ a2,
                              const float* __restrict__ cent, const float* __restrict__ updated,
                              float* __restrict__ out, const int N, const int total)
{
    const int g = blockIdx.x * 256 + threadIdx.x;
    if (g >= total) return;
    const bool match = (*mismatch == 0u);
    if (g < N)       out[g] = (float)(match ? a2[g] : a1[g]);
    else if (g == N) out[g] = match ? 1.0f : 0.0f;
    else {
        const int e = g - N - 1;
        out[g] = match ? updated[e] : cent[e];
    }
}

extern "C" void kernel_launch(void* const* d_in, const int* in_sizes, int n_in,
                              void* d_out, int out_size, void* d_ws, size_t ws_size,
                              hipStream_t stream)
{
    const float* x    = (const float*)d_in[0];
    const float* cent = (const float*)d_in[1];
    const int*   prev = (const int*)d_in[2];
    const int N = in_sizes[0] / DD;
    const int pstride = (n_in >= 3 && in_sizes[2] >= 2 * N) ? 2 : 1;  // int64 defensive

    char* ws = (char*)d_ws;
    size_t off = 0;
    auto alloc = [&](size_t b) { void* p = ws + off; off += (b + 255) & ~(size_t)255; return p; };
    int*   assign1 = (int*)alloc((size_t)N * 4);
    int*   assign2 = (int*)alloc((size_t)N * 4);
    float* cc      = (float*)alloc(KK * 4);
    float* cc2v    = (float*)alloc(KK * 4);
    int*   counts  = (int*)alloc(KK * 4);
    int*   starts  = (int*)alloc(KK * 4);
    int*   cursor  = (int*)alloc(KK * 4);
    int*   idx     = (int*)alloc((size_t)N * 4);
    unsigned long long* sums = (unsigned long long*)alloc((size_t)KK * DD * 8);
    float* updated = (float*)alloc((size_t)KK * DD * 4);
    unsigned int* mismatch = (unsigned int*)alloc(256);

    hipMemsetAsync(counts, 0, KK * 4, stream);
    hipMemsetAsync(sums, 0, (size_t)KK * DD * 8, stream);
    hipMemsetAsync(mismatch, 0, 4, stream);

    sqnorm_kernel<<<(KK + 3) / 4, 256, 0, stream>>>(cent, cc, KK);

    const int gb = (N + TM - 1) / TM;
    argmin_kernel<true><<<gb, 256, 0, stream>>>(x, cent, cc, N, assign1,
                                                prev, pstride, mismatch, counts);

    // counting-sort + gather segment sum (hist fused into argmin pass 1)
    scan_kernel<<<1, KK, 0, stream>>>(counts, starts, cursor);
    scatter_kernel<<<(N + 255) / 256, 256, 0, stream>>>(assign1, cursor, idx, N);
    gather_kernel<<<KK * SPLIT, 256, 0, stream>>>(x, idx, starts, counts, sums);

    update_kernel<<<KK, 256, 0, stream>>>(cent, sums, counts, updated, cc2v);

    argmin_kernel<false><<<gb, 256, 0, stream>>>(x, updated, cc2v, N, assign2,
                                                 nullptr, 1, nullptr, nullptr);

    output_kernel<<<(out_size + 255) / 256, 256, 0, stream>>>(mismatch, assign1, assign2,
                                                              cent, updated, (float*)d_out,
                                                              N, out_size);
}